// Round 15
// baseline (311.509 us; speedup 1.0000x reference)
//
#include <hip/hip_runtime.h>
#include <stdint.h>

#define S_LEN 1024
#define HDIM  4096
#define NHEAD 32
#define DHEAD 128
#define BATCH 2
#define MTOK  (BATCH * S_LEN)   // 2048

typedef __attribute__((ext_vector_type(4))) int   i32x4;
typedef __attribute__((ext_vector_type(4))) float f32x4;
typedef __attribute__((ext_vector_type(8))) short bf16x8;

#define GLOBAL_AS __attribute__((address_space(1)))
#define LDS_AS    __attribute__((address_space(3)))

__device__ __forceinline__ void gl2lds16(const void* g, void* l) {
  __builtin_amdgcn_global_load_lds((const GLOBAL_AS unsigned int*)(g),
                                   (LDS_AS unsigned int*)(l), 16, 0, 0);
}

// float -> bf16 bits, round-to-nearest-even
__device__ __forceinline__ unsigned short f2bf(float f) {
  unsigned int u = __float_as_uint(f);
  unsigned int r = (u + 0x7fffu + ((u >> 16) & 1u)) >> 16;
  return (unsigned short)r;
}

#define PIN4(v) asm volatile("" : "+v"(v.x), "+v"(v.y), "+v"(v.z), "+v"(v.w))

// -------- merged input fake-quant, block-per-row, pinned registers --------
__global__ __launch_bounds__(256) void prequant_kernel(
    const float* __restrict__ hs,
    const float* __restrict__ w0, const float* __restrict__ w1,
    const float* __restrict__ w2, const float* __restrict__ w3,
    int8_t* __restrict__ xq8,
    int8_t* __restrict__ q0, int8_t* __restrict__ q1,
    int8_t* __restrict__ q2, int8_t* __restrict__ q3,
    float* __restrict__ sx,
    float* __restrict__ s0, float* __restrict__ s1,
    float* __restrict__ s2, float* __restrict__ s3)
{
  const int row = blockIdx.x;
  const float* src; int8_t* dst; float* sc; float qmax, clipLo; int lrow;
  if (row < MTOK) {
    src = hs; dst = xq8; sc = sx; qmax = 127.f; clipLo = -128.f; lrow = row;
  } else {
    const int wi = (row - MTOK) >> 12;
    lrow = (row - MTOK) & 4095;
    qmax = 7.f; clipLo = -8.f;
    src = (wi == 0) ? w0 : (wi == 1) ? w1 : (wi == 2) ? w2 : w3;
    dst = (wi == 0) ? q0 : (wi == 1) ? q1 : (wi == 2) ? q2 : q3;
    sc  = (wi == 0) ? s0 : (wi == 1) ? s1 : (wi == 2) ? s2 : s3;
  }
  const int t = threadIdx.x;
  const float4* xr = (const float4*)(src + (size_t)lrow * HDIM);
  float4 v[4];
  float am = 0.f;
#pragma unroll
  for (int i = 0; i < 4; ++i) {
    v[i] = xr[t + 256 * i];
    am = fmaxf(am, fmaxf(fmaxf(fabsf(v[i].x), fabsf(v[i].y)),
                         fmaxf(fabsf(v[i].z), fabsf(v[i].w))));
  }
#pragma unroll
  for (int i = 0; i < 4; ++i) PIN4(v[i]);
#pragma unroll
  for (int off = 32; off > 0; off >>= 1) am = fmaxf(am, __shfl_down(am, off));
  __shared__ float wred[4];
  if ((t & 63) == 0) wred[t >> 6] = am;
  __syncthreads();
  const float m = fmaxf(fmaxf(wred[0], wred[1]), fmaxf(wred[2], wred[3]));
  const float scale = fmaxf(m / qmax, 1e-8f);
  const float inv = 1.0f / scale;
  if (t == 0) sc[lrow] = scale;
  int* qo = (int*)(dst + (size_t)lrow * HDIM);
#pragma unroll
  for (int i = 0; i < 4; ++i) {
    const int b0 = (int)fminf(fmaxf(rintf(v[i].x * inv), clipLo), qmax);
    const int b1 = (int)fminf(fmaxf(rintf(v[i].y * inv), clipLo), qmax);
    const int b2 = (int)fminf(fmaxf(rintf(v[i].z * inv), clipLo), qmax);
    const int b3 = (int)fminf(fmaxf(rintf(v[i].w * inv), clipLo), qmax);
    qo[t + 256 * i] = (b0 & 0xff) | ((b1 & 0xff) << 8) | ((b2 & 0xff) << 16) | ((b3 & 0xff) << 24);
  }
}

// -------- per-row fake-quant for attn output --------
__global__ __launch_bounds__(256) void rowquant_kernel(
    const float* __restrict__ x, int8_t* __restrict__ q,
    float* __restrict__ scales, float qmax, float clipLo)
{
  const int row = blockIdx.x;
  const int t = threadIdx.x;
  const float4* xr = (const float4*)(x + (size_t)row * HDIM);
  float4 v[4];
  float am = 0.f;
#pragma unroll
  for (int i = 0; i < 4; ++i) {
    v[i] = xr[t + 256 * i];
    am = fmaxf(am, fmaxf(fmaxf(fabsf(v[i].x), fabsf(v[i].y)),
                         fmaxf(fabsf(v[i].z), fabsf(v[i].w))));
  }
#pragma unroll
  for (int i = 0; i < 4; ++i) PIN4(v[i]);
#pragma unroll
  for (int off = 32; off > 0; off >>= 1) am = fmaxf(am, __shfl_down(am, off));
  __shared__ float wred[4];
  if ((t & 63) == 0) wred[t >> 6] = am;
  __syncthreads();
  const float m = fmaxf(fmaxf(wred[0], wred[1]), fmaxf(wred[2], wred[3]));
  const float scale = fmaxf(m / qmax, 1e-8f);
  const float inv = 1.0f / scale;
  if (t == 0) scales[row] = scale;
  int* qo = (int*)(q + (size_t)row * HDIM);
#pragma unroll
  for (int i = 0; i < 4; ++i) {
    const int b0 = (int)fminf(fmaxf(rintf(v[i].x * inv), clipLo), qmax);
    const int b1 = (int)fminf(fmaxf(rintf(v[i].y * inv), clipLo), qmax);
    const int b2 = (int)fminf(fmaxf(rintf(v[i].z * inv), clipLo), qmax);
    const int b3 = (int)fminf(fmaxf(rintf(v[i].w * inv), clipLo), qmax);
    qo[t + 256 * i] = (b0 & 0xff) | ((b1 & 0xff) << 8) | ((b2 & 0xff) << 16) | ((b3 & 0xff) << 24);
  }
}

// -------- RoPE cos/sin tables: [1024][64] each --------
__global__ __launch_bounds__(256) void ropetab_kernel(
    float* __restrict__ ct, float* __restrict__ st)
{
  const int t = blockIdx.x * 256 + threadIdx.x;
  const int s = t >> 6, d = t & 63;
  const float inv = powf(10000.0f, -(float)d * (1.0f / 64.0f));
  const float ang = (float)s * inv;
  float sn, c;
  sincosf(ang, &sn, &c);
  ct[t] = c;
  st[t] = sn;
}

// ======== merged QKV i8 MFMA GEMM: 1536 blocks, z selects weight + epilogue ========
__global__ __launch_bounds__(256, 2) void gemm_qkv_fused_kernel(
    const int8_t* __restrict__ A, const float* __restrict__ sa,
    const int8_t* __restrict__ w0, const int8_t* __restrict__ w1,
    const int8_t* __restrict__ w2,
    const float* __restrict__ sw0, const float* __restrict__ sw1,
    const float* __restrict__ sw2,
    int8_t* __restrict__ qq8, float* __restrict__ sqs,
    int8_t* __restrict__ kq8, float* __restrict__ sks,
    unsigned short* __restrict__ vqT,
    const float* __restrict__ ctab, const float* __restrict__ stab)
{
  __shared__ __align__(16) char smem[128 * 129 * 4];
  __shared__ float vscale[128];
  __shared__ float vinv[128];
  int8_t (*asB)[128 * 128] = (int8_t(*)[128 * 128])smem;
  int8_t (*bsB)[128 * 128] = (int8_t(*)[128 * 128])(smem + 32768);
  float (*fx)[129] = (float(*)[129])smem;

  // bijective XCD-chunked swizzle over 1536 blocks (192/XCD)
  const int flat = blockIdx.x;
  const int nf = (flat & 7) * 192 + (flat >> 3);
  const int z = nf >> 9;            // 0,1,2
  const int rr = nf & 511;
  const int bmi = rr & 15, bni = rr >> 4;
  const int bm = bmi * 128, bn = bni * 128;

  const int8_t* Bw = (z == 0) ? w0 : (z == 1) ? w1 : w2;
  const float* sb = (z == 0) ? sw0 : (z == 1) ? sw1 : sw2;

  const int tid = threadIdx.x;
  const int w = tid >> 6, l = tid & 63;
  const int l15 = l & 15, lg = l >> 4, l7 = l & 7;
  const int lr = l >> 3, g7 = l & 7;
  const int m0 = (w >> 1) * 64, n0 = (w & 1) * 64;

  const int8_t* aT = A + (size_t)(bm + lr) * HDIM + ((g7 ^ lr) << 4);
  const int8_t* bT = Bw + (size_t)(bn + lr) * HDIM + ((g7 ^ lr) << 4);

  i32x4 acc[4][4];
#pragma unroll
  for (int i = 0; i < 4; ++i)
#pragma unroll
    for (int j = 0; j < 4; ++j) acc[i][j] = (i32x4){0, 0, 0, 0};

  auto stage = [&](int t) {
    const int bf = t & 1;
    const size_t k = (size_t)t * 128;
#pragma unroll
    for (int i = 0; i < 4; ++i) {
      const int r0 = w * 32 + i * 8;
      gl2lds16(aT + (size_t)r0 * HDIM + k, asB[bf] + r0 * 128);
      gl2lds16(bT + (size_t)r0 * HDIM + k, bsB[bf] + r0 * 128);
    }
  };

  stage(0);
  asm volatile("s_waitcnt vmcnt(0)" ::: "memory");
  __builtin_amdgcn_s_barrier();

  for (int t = 0; t < 32; ++t) {
    if (t < 31) stage(t + 1);
    const int cur = t & 1;
    __builtin_amdgcn_s_setprio(1);
#pragma unroll
    for (int kk = 0; kk < 2; ++kk) {
      i32x4 aF[4], bF[4];
      const int slot = (((kk << 2) + lg) ^ l7) << 4;
#pragma unroll
      for (int i = 0; i < 4; ++i)
        aF[i] = *(const i32x4*)(asB[cur] + (m0 + i * 16 + l15) * 128 + slot);
#pragma unroll
      for (int j = 0; j < 4; ++j)
        bF[j] = *(const i32x4*)(bsB[cur] + (n0 + j * 16 + l15) * 128 + slot);
#pragma unroll
      for (int i = 0; i < 4; ++i)
#pragma unroll
        for (int j = 0; j < 4; ++j)
          acc[i][j] = __builtin_amdgcn_mfma_i32_16x16x64_i8(aF[i], bF[j], acc[i][j], 0, 0, 0);
    }
    __builtin_amdgcn_s_setprio(0);
    if (t < 31) {
      asm volatile("s_waitcnt vmcnt(0)" ::: "memory");
      __builtin_amdgcn_s_barrier();
    }
  }

  float sbr[4];
#pragma unroll
  for (int j = 0; j < 4; ++j) sbr[j] = sb[bn + n0 + j * 16 + l15];

  // ---- scatter scaled f32 tile to LDS ----
  __syncthreads();
#pragma unroll
  for (int i = 0; i < 4; ++i) {
#pragma unroll
    for (int r = 0; r < 4; ++r) {
      const int ml = m0 + i * 16 + lg * 4 + r;
      const float sm = sa[bm + ml];
#pragma unroll
      for (int j = 0; j < 4; ++j)
        fx[ml][n0 + j * 16 + l15] = sm * sbr[j] * (float)acc[i][j][r];
    }
  }
  __syncthreads();

  const int h = bn >> 7;

  if (z <= 1) {
    // rope + per-(token,head) quant8 -> qq8/kq8
    const int row = tid >> 1, half = tid & 1;
    const int sg = bm + row;
    const int b = sg >> 10, s = sg & (S_LEN - 1);
    const float* ct = ctab + (size_t)s * 64;
    const float* st = stab + (size_t)s * 64;
    float am = 0.f;
#pragma unroll
    for (int d0 = 0; d0 < 64; ++d0) {
      const int d = half * 64 + d0;
      const float x0 = fx[row][d];
      const float x1 = fx[row][d ^ 64];
      const float c = ct[d0], sn = st[d0];
      const float v = half ? (x0 * c + x1 * sn) : (x0 * c - x1 * sn);
      fx[row][d] = v;
      am = fmaxf(am, fabsf(v));
    }
    am = fmaxf(am, __shfl_xor(am, 1));
    const float scale = fmaxf(am * (1.0f / 127.0f), 1e-8f);
    const float inv = 1.0f / scale;
    int8_t* dst = (z == 0) ? qq8 : kq8;
    float* osc = (z == 0) ? sqs : sks;
    int8_t* op = dst + (((size_t)(b * NHEAD + h)) * S_LEN + s) * DHEAD + half * 64;
#pragma unroll
    for (int c4 = 0; c4 < 4; ++c4) {
      i32x4 dw;
#pragma unroll
      for (int u = 0; u < 4; ++u) {
        int pk = 0;
#pragma unroll
        for (int bi = 0; bi < 4; ++bi) {
          const float v = fx[row][half * 64 + c4 * 16 + u * 4 + bi];
          const int q = (int)fminf(fmaxf(rintf(v * inv), -128.f), 127.f);
          pk |= (q & 0xff) << (8 * bi);
        }
        dw[u] = pk;
      }
      *(i32x4*)(op + c4 * 16) = dw;
    }
    if (!half) osc[((size_t)(b * NHEAD + h)) * S_LEN + s] = scale;
  } else {
    // V: per-(token,head) quant + fold + transpose to [bh][d][s] bf16
    {
      const int row = tid >> 1, half = tid & 1;
      float am = 0.f;
#pragma unroll
      for (int d0 = 0; d0 < 64; ++d0)
        am = fmaxf(am, fabsf(fx[row][half * 64 + d0]));
      am = fmaxf(am, __shfl_xor(am, 1));
      if (!half) {
        const float s = fmaxf(am * (1.0f / 127.0f), 1e-8f);
        vscale[row] = s;
        vinv[row] = 1.0f / s;
      }
    }
    __syncthreads();
    {
      const int d = tid >> 1, sh = tid & 1;
      const int b = bm >> 10;
      const int bh = b * NHEAD + h;
      unsigned short* op = vqT + ((size_t)bh * DHEAD + d) * S_LEN + (bm & (S_LEN - 1)) + sh * 64;
#pragma unroll
      for (int c8 = 0; c8 < 8; ++c8) {
        i32x4 dw;
#pragma unroll
        for (int u = 0; u < 4; ++u) {
          const int sl = sh * 64 + c8 * 8 + u * 2;
          const float sc0 = vscale[sl], sc1 = vscale[sl + 1];
          const float q0 = fminf(fmaxf(rintf(fx[sl][d] * vinv[sl]), -128.f), 127.f);
          const float q1 = fminf(fmaxf(rintf(fx[sl + 1][d] * vinv[sl + 1]), -128.f), 127.f);
          dw[u] = (int)f2bf(q0 * sc0) | ((int)f2bf(q1 * sc1) << 16);
        }
        *(i32x4*)(op + c8 * 8) = dw;
      }
    }
  }
}

// ======== wo GEMM: 128x128, 4 waves, 2-phase dbuf, plain C epilogue ========
__global__ __launch_bounds__(256, 2) void gemm_wo_kernel(
    const int8_t* __restrict__ A, const float* __restrict__ sa,
    const int8_t* __restrict__ Bw, const float* __restrict__ sb,
    float* __restrict__ C)
{
  __shared__ __align__(16) int8_t asB[2][128 * 128];
  __shared__ __align__(16) int8_t bsB[2][128 * 128];

  const int flat = blockIdx.y * gridDim.x + blockIdx.x;
  const int nf = (flat & 7) * 64 + (flat >> 3);
  const int bmi = nf & 15, bni = nf >> 4;
  const int bm = bmi * 128, bn = bni * 128;

  const int tid = threadIdx.x;
  const int w = tid >> 6, l = tid & 63;
  const int l15 = l & 15, lg = l >> 4, l7 = l & 7;
  const int lr = l >> 3, g7 = l & 7;
  const int m0 = (w >> 1) * 64, n0 = (w & 1) * 64;

  const int8_t* aT = A + (size_t)(bm + lr) * HDIM + ((g7 ^ lr) << 4);
  const int8_t* bT = Bw + (size_t)(bn + lr) * HDIM + ((g7 ^ lr) << 4);

  i32x4 acc[4][4];
#pragma unroll
  for (int i = 0; i < 4; ++i)
#pragma unroll
    for (int j = 0; j < 4; ++j) acc[i][j] = (i32x4){0, 0, 0, 0};

  auto stage = [&](int t) {
    const int bf = t & 1;
    const size_t k = (size_t)t * 128;
#pragma unroll
    for (int i = 0; i < 4; ++i) {
      const int r0 = w * 32 + i * 8;
      gl2lds16(aT + (size_t)r0 * HDIM + k, asB[bf] + r0 * 128);
      gl2lds16(bT + (size_t)r0 * HDIM + k, bsB[bf] + r0 * 128);
    }
  };

  stage(0);
  asm volatile("s_waitcnt vmcnt(0)" ::: "memory");
  __builtin_amdgcn_s_barrier();

  for (int t = 0; t < 32; ++t) {
    if (t < 31) stage(t + 1);
    const int cur = t & 1;
    __builtin_amdgcn_s_setprio(1);
#pragma unroll
    for (int kk = 0; kk < 2; ++kk) {
      i32x4 aF[4], bF[4];
      const int slot = (((kk << 2) + lg) ^ l7) << 4;
#pragma unroll
      for (int i = 0; i < 4; ++i)
        aF[i] = *(const i32x4*)(asB[cur] + (m0 + i * 16 + l15) * 128 + slot);
#pragma unroll
      for (int j = 0; j < 4; ++j)
        bF[j] = *(const i32x4*)(bsB[cur] + (n0 + j * 16 + l15) * 128 + slot);
#pragma unroll
      for (int i = 0; i < 4; ++i)
#pragma unroll
        for (int j = 0; j < 4; ++j)
          acc[i][j] = __builtin_amdgcn_mfma_i32_16x16x64_i8(aF[i], bF[j], acc[i][j], 0, 0, 0);
    }
    __builtin_amdgcn_s_setprio(0);
    if (t < 31) {
      asm volatile("s_waitcnt vmcnt(0)" ::: "memory");
      __builtin_amdgcn_s_barrier();
    }
  }

  float sbr[4];
#pragma unroll
  for (int j = 0; j < 4; ++j) sbr[j] = sb[bn + n0 + j * 16 + l15];
#pragma unroll
  for (int i = 0; i < 4; ++i) {
#pragma unroll
    for (int r = 0; r < 4; ++r) {
      const int m = bm + m0 + i * 16 + lg * 4 + r;
      const float sm = sa[m];
      float* cp = C + (size_t)m * HDIM + bn + n0 + l15;
#pragma unroll
      for (int j = 0; j < 4; ++j)
        cp[j * 16] = sm * sbr[j] * (float)acc[i][j][r];
    }
  }
}

// -------- single-pass online attn, K/V double-buffered, defer-max --------
#define QB 64
#define KB 64

__global__ __launch_bounds__(256) void attn_mfma_kernel(
    const int8_t* __restrict__ qq, const float* __restrict__ sq,
    const int8_t* __restrict__ kq, const float* __restrict__ sk,
    const unsigned short* __restrict__ vqT,
    float* __restrict__ attn)
{
  __shared__ __align__(16) int8_t ks[2][KB * 128];
  __shared__ __align__(16) unsigned short vs[2][128 * 64];
  __shared__ __align__(16) unsigned short ps[QB][64];

  const int tid = threadIdx.x;
  const int w = tid >> 6;
  const int l = tid & 63;
  const int l15 = l & 15;
  const int lg = l >> 4;
  const int lr = l >> 3, g7 = l & 7;
  const int bflat = blockIdx.x;
  const int bh = (bflat & 7) + 8 * (bflat >> 6);
  const int qxb = (bflat >> 3) & 7;
  const size_t bhS = (size_t)bh * S_LEN;
  const int b = bh >> 5, h = bh & 31;
  const int NT = S_LEN / QB;

  auto stageKV = [&](int kt, int nb) {
    const int k0 = kt * KB;
#pragma unroll
    for (int i = 0; i < 2; ++i) {
      const int r0 = w * 16 + i * 8;
      gl2lds16(kq + (bhS + k0 + r0 + lr) * (size_t)128 + ((g7 ^ lr) << 4),
               ks[nb] + r0 * 128);
    }
#pragma unroll
    for (int i = 0; i < 4; ++i) {
      const int r0 = w * 32 + i * 8;
      gl2lds16(vqT + ((size_t)bh * 128 + r0 + lr) * S_LEN + k0 + ((g7 ^ lr) << 3),
               vs[nb] + r0 * 64);
    }
  };

  for (int rep = 0; rep < 2; ++rep) {
    const int qt = rep ? (NT - 1 - qxb) : qxb;
    const int q0 = qt * QB;
    const int nkt = qt + 1;

    const int qrow = q0 + w * 16 + l15;
    const int8_t* qp = qq + (bhS + qrow) * (size_t)DHEAD;
    const i32x4 qa0 = *(const i32x4*)(qp + lg * 16);
    const i32x4 qa1 = *(const i32x4*)(qp + 64 + lg * 16);

    float sqv[4];
    int qg[4];
#pragma unroll
    for (int r = 0; r < 4; ++r) {
      qg[r] = q0 + w * 16 + lg * 4 + r;
      sqv[r] = sq[bhS + qg[r]] * 0.08838834764831843f * 1.4426950408889634f;
    }

    float m_run[4] = {-3.0e38f, -3.0e38f, -3.0e38f, -3.0e38f};
    float rs[4] = {0.f, 0.f, 0.f, 0.f};
    f32x4 oacc[8];
#pragma unroll
    for (int ds = 0; ds < 8; ++ds) oacc[ds] = (f32x4){0.f, 0.f, 0.f, 0.f};

    const int qloc = w * 16 + l15;
    const int swA0 = (lg ^ (qloc & 7)) << 3;
    const int swA1 = ((lg + 4) ^ (qloc & 7)) << 3;

    stageKV(0, 0);
    float skn[4];
#pragma unroll
    for (int c = 0; c < 4; ++c) skn[c] = sk[bhS + c * 16 + l15];
    asm volatile("s_waitcnt vmcnt(0)" ::: "memory");
    __builtin_amdgcn_s_barrier();

    int nb = 0;
    for (int kt = 0; kt < nkt; ++kt) {
      const int k0 = kt * KB;
      float skc[4];
#pragma unroll
      for (int c = 0; c < 4; ++c) skc[c] = skn[c];
      if (kt + 1 < nkt) {
        stageKV(kt + 1, nb ^ 1);
#pragma unroll
        for (int c = 0; c < 4; ++c)
          skn[c] = sk[bhS + (kt + 1) * KB + c * 16 + l15];
      }
      const bool diag = (kt == nkt - 1);

      float s2v[4][4];
      float tmax[4] = {-3.0e38f, -3.0e38f, -3.0e38f, -3.0e38f};
      __builtin_amdgcn_s_setprio(1);
#pragma unroll
      for (int c = 0; c < 4; ++c) {
        const int krow = c * 16 + l15;
        const i32x4 b0 = *(const i32x4*)(ks[nb] + krow * 128 + ((lg ^ (krow & 7)) << 4));
        const i32x4 b1 = *(const i32x4*)(ks[nb] + krow * 128 + (((lg + 4) ^ (krow & 7)) << 4));
        i32x4 acc = {0, 0, 0, 0};
        acc = __builtin_amdgcn_mfma_i32_16x16x64_i8(qa0, b0, acc, 0, 0, 0);
        acc = __builtin_amdgcn_mfma_i32_16x16x64_i8(qa1, b1, acc, 0, 0, 0);
        const int kgl = k0 + krow;
#pragma unroll
        for (int r = 0; r < 4; ++r) {
          const bool valid = !diag || (kgl <= qg[r]);
          const float s2 = valid ? ((float)acc[r] * sqv[r] * skc[c]) : -3.0e38f;
          s2v[c][r] = s2;
          tmax[r] = fmaxf(tmax[r], s2);
        }
      }
      __builtin_amdgcn_s_setprio(0);
#pragma unroll
      for (int r = 0; r < 4; ++r)
#pragma unroll
        for (int off = 1; off < 16; off <<= 1)
          tmax[r] = fmaxf(tmax[r], __shfl_xor(tmax[r], off));

#pragma unroll
      for (int r = 0; r < 4; ++r) {
        if (tmax[r] > m_run[r] + 8.0f) {
          const float f = exp2f(m_run[r] - tmax[r]);
          m_run[r] = tmax[r];
          rs[r] *= f;
#pragma unroll
          for (int ds = 0; ds < 8; ++ds) oacc[ds][r] *= f;
        }
      }

#pragma unroll
      for (int c = 0; c < 4; ++c) {
        const int krow = c * 16 + l15;
#pragma unroll
        for (int r = 0; r < 4; ++r) {
          const float e = exp2f(s2v[c][r] - m_run[r]);
          rs[r] += e;
          const float p = rintf(e * 127.0f);
          const int qr = w * 16 + lg * 4 + r;
          const int sidx = (((krow >> 3) ^ (qr & 7)) << 3) | (krow & 7);
          ps[qr][sidx] = f2bf(p);
        }
      }

      const bf16x8 a0 = *(const bf16x8*)&ps[qloc][swA0];
      const bf16x8 a1 = *(const bf16x8*)&ps[qloc][swA1];
      __builtin_amdgcn_s_setprio(1);
#pragma unroll
      for (int ds = 0; ds < 8; ++ds) {
        const int d = ds * 16 + l15;
        const bf16x8 bv0 = *(const bf16x8*)(vs[nb] + d * 64 + ((lg ^ (d & 7)) << 3));
        const bf16x8 bv1 = *(const bf16x8*)(vs[nb] + d * 64 + (((lg + 4) ^ (d & 7)) << 3));
        oacc[ds] = __builtin_amdgcn_mfma_f32_16x16x32_bf16(a0, bv0, oacc[ds], 0, 0, 0);
        oacc[ds] = __builtin_amdgcn_mfma_f32_16x16x32_bf16(a1, bv1, oacc[ds], 0, 0, 0);
      }
      __builtin_amdgcn_s_setprio(0);
      asm volatile("s_waitcnt vmcnt(0)" ::: "memory");
      __builtin_amdgcn_s_barrier();
      nb ^= 1;
    }

#pragma unroll
    for (int r = 0; r < 4; ++r)
#pragma unroll
      for (int off = 1; off < 16; off <<= 1)
        rs[r] += __shfl_xor(rs[r], off);

#pragma unroll
    for (int r = 0; r < 4; ++r) {
      const float inv = 1.0f / (127.0f * rs[r]);
      float* op = attn + ((size_t)(b * S_LEN + qg[r])) * HDIM + h * DHEAD + l15;
#pragma unroll
      for (int ds = 0; ds < 8; ++ds)
        op[ds * 16] = oacc[ds][r] * inv;
    }
  }
}

extern "C" void kernel_launch(void* const* d_in, const int* in_sizes, int n_in,
                              void* d_out, int out_size, void* d_ws, size_t ws_size,
                              hipStream_t stream) {
  const float* hs = (const float*)d_in[0];
  const float* wmat[4] = { (const float*)d_in[1], (const float*)d_in[2],
                           (const float*)d_in[3], (const float*)d_in[4] };

  char* p = (char*)d_ws;
  auto take = [&](size_t sz) { char* r = p; p += (sz + 255) & ~(size_t)255; return r; };

  int8_t* xq8 = (int8_t*)take((size_t)MTOK * HDIM);
  int8_t* w4[4];
  for (int i = 0; i < 4; ++i) w4[i] = (int8_t*)take((size_t)HDIM * HDIM);
  float* sx = (float*)take((size_t)MTOK * 4);
  float* sw[4];
  for (int i = 0; i < 4; ++i) sw[i] = (float*)take((size_t)HDIM * 4);
  float* y = (float*)take((size_t)MTOK * HDIM * 4);
  int8_t* qq8 = (int8_t*)take((size_t)MTOK * HDIM);
  int8_t* kq8 = (int8_t*)take((size_t)MTOK * HDIM);
  unsigned short* vqT = (unsigned short*)take((size_t)MTOK * HDIM * 2);
  float* sqs = (float*)take((size_t)BATCH * NHEAD * S_LEN * 4);
  float* sks = (float*)take((size_t)BATCH * NHEAD * S_LEN * 4);
  float* sattn = (float*)take((size_t)MTOK * 4);
  float* ctab = (float*)take((size_t)S_LEN * 64 * 4);
  float* stab = (float*)take((size_t)S_LEN * 64 * 4);

  prequant_kernel<<<MTOK + 4 * HDIM, 256, 0, stream>>>(
      hs, wmat[0], wmat[1], wmat[2], wmat[3],
      xq8, w4[0], w4[1], w4[2], w4[3],
      sx, sw[0], sw[1], sw[2], sw[3]);
  ropetab_kernel<<<S_LEN * 64 / 256, 256, 0, stream>>>(ctab, stab);

  // merged QKV: one 1536-block dispatch
  gemm_qkv_fused_kernel<<<1536, 256, 0, stream>>>(
      xq8, sx, w4[0], w4[1], w4[2], sw[0], sw[1], sw[2],
      qq8, sqs, kq8, sks, vqT, ctab, stab);

  attn_mfma_kernel<<<512, 256, 0, stream>>>(qq8, sqs, kq8, sks, vqT, y);

  rowquant_kernel<<<MTOK, 256, 0, stream>>>(y, xq8, sattn, 127.f, -128.f);
  const dim3 gg(HDIM / 128, MTOK / 128);
  gemm_wo_kernel<<<gg, 256, 0, stream>>>(xq8, sattn, w4[3], sw[3], (float*)d_out);
}

// Round 16
// 293.286 us; speedup vs baseline: 1.0621x; 1.0621x over previous
//
#include <hip/hip_runtime.h>
#include <stdint.h>

#define S_LEN 1024
#define HDIM  4096
#define NHEAD 32
#define DHEAD 128
#define BATCH 2
#define MTOK  (BATCH * S_LEN)   // 2048

typedef __attribute__((ext_vector_type(4))) int   i32x4;
typedef __attribute__((ext_vector_type(4))) float f32x4;
typedef __attribute__((ext_vector_type(8))) short bf16x8;

#define GLOBAL_AS __attribute__((address_space(1)))
#define LDS_AS    __attribute__((address_space(3)))

__device__ __forceinline__ void gl2lds16(const void* g, void* l) {
  __builtin_amdgcn_global_load_lds((const GLOBAL_AS unsigned int*)(g),
                                   (LDS_AS unsigned int*)(l), 16, 0, 0);
}

// float -> bf16 bits, round-to-nearest-even
__device__ __forceinline__ unsigned short f2bf(float f) {
  unsigned int u = __float_as_uint(f);
  unsigned int r = (u + 0x7fffu + ((u >> 16) & 1u)) >> 16;
  return (unsigned short)r;
}

#define PIN4(v) asm volatile("" : "+v"(v.x), "+v"(v.y), "+v"(v.z), "+v"(v.w))

// -------- merged input fake-quant + rope-table build (extra 256 blocks) --------
__global__ __launch_bounds__(256) void prequant_kernel(
    const float* __restrict__ hs,
    const float* __restrict__ w0, const float* __restrict__ w1,
    const float* __restrict__ w2, const float* __restrict__ w3,
    int8_t* __restrict__ xq8,
    int8_t* __restrict__ q0, int8_t* __restrict__ q1,
    int8_t* __restrict__ q2, int8_t* __restrict__ q3,
    float* __restrict__ sx,
    float* __restrict__ s0, float* __restrict__ s1,
    float* __restrict__ s2, float* __restrict__ s3,
    float* __restrict__ ctab, float* __restrict__ stab)
{
  const int row = blockIdx.x;
  if (row >= MTOK + 4 * HDIM) {
    // rope tables: [1024][64] cos/sin
    const int t = (row - (MTOK + 4 * HDIM)) * 256 + threadIdx.x;
    const int s = t >> 6, d = t & 63;
    const float inv = powf(10000.0f, -(float)d * (1.0f / 64.0f));
    const float ang = (float)s * inv;
    float sn, c;
    sincosf(ang, &sn, &c);
    ctab[t] = c;
    stab[t] = sn;
    return;
  }
  const float* src; int8_t* dst; float* sc; float qmax, clipLo; int lrow;
  if (row < MTOK) {
    src = hs; dst = xq8; sc = sx; qmax = 127.f; clipLo = -128.f; lrow = row;
  } else {
    const int wi = (row - MTOK) >> 12;
    lrow = (row - MTOK) & 4095;
    qmax = 7.f; clipLo = -8.f;
    src = (wi == 0) ? w0 : (wi == 1) ? w1 : (wi == 2) ? w2 : w3;
    dst = (wi == 0) ? q0 : (wi == 1) ? q1 : (wi == 2) ? q2 : q3;
    sc  = (wi == 0) ? s0 : (wi == 1) ? s1 : (wi == 2) ? s2 : s3;
  }
  const int t = threadIdx.x;
  const float4* xr = (const float4*)(src + (size_t)lrow * HDIM);
  float4 v[4];
  float am = 0.f;
#pragma unroll
  for (int i = 0; i < 4; ++i) {
    v[i] = xr[t + 256 * i];
    am = fmaxf(am, fmaxf(fmaxf(fabsf(v[i].x), fabsf(v[i].y)),
                         fmaxf(fabsf(v[i].z), fabsf(v[i].w))));
  }
#pragma unroll
  for (int i = 0; i < 4; ++i) PIN4(v[i]);
#pragma unroll
  for (int off = 32; off > 0; off >>= 1) am = fmaxf(am, __shfl_down(am, off));
  __shared__ float wred[4];
  if ((t & 63) == 0) wred[t >> 6] = am;
  __syncthreads();
  const float m = fmaxf(fmaxf(wred[0], wred[1]), fmaxf(wred[2], wred[3]));
  const float scale = fmaxf(m / qmax, 1e-8f);
  const float inv = 1.0f / scale;
  if (t == 0) sc[lrow] = scale;
  int* qo = (int*)(dst + (size_t)lrow * HDIM);
#pragma unroll
  for (int i = 0; i < 4; ++i) {
    const int b0 = (int)fminf(fmaxf(rintf(v[i].x * inv), clipLo), qmax);
    const int b1 = (int)fminf(fmaxf(rintf(v[i].y * inv), clipLo), qmax);
    const int b2 = (int)fminf(fmaxf(rintf(v[i].z * inv), clipLo), qmax);
    const int b3 = (int)fminf(fmaxf(rintf(v[i].w * inv), clipLo), qmax);
    qo[t + 256 * i] = (b0 & 0xff) | ((b1 & 0xff) << 8) | ((b2 & 0xff) << 16) | ((b3 & 0xff) << 24);
  }
}

// -------- per-row fake-quant for attn output --------
__global__ __launch_bounds__(256) void rowquant_kernel(
    const float* __restrict__ x, int8_t* __restrict__ q,
    float* __restrict__ scales, float qmax, float clipLo)
{
  const int row = blockIdx.x;
  const int t = threadIdx.x;
  const float4* xr = (const float4*)(x + (size_t)row * HDIM);
  float4 v[4];
  float am = 0.f;
#pragma unroll
  for (int i = 0; i < 4; ++i) {
    v[i] = xr[t + 256 * i];
    am = fmaxf(am, fmaxf(fmaxf(fabsf(v[i].x), fabsf(v[i].y)),
                         fmaxf(fabsf(v[i].z), fabsf(v[i].w))));
  }
#pragma unroll
  for (int i = 0; i < 4; ++i) PIN4(v[i]);
#pragma unroll
  for (int off = 32; off > 0; off >>= 1) am = fmaxf(am, __shfl_down(am, off));
  __shared__ float wred[4];
  if ((t & 63) == 0) wred[t >> 6] = am;
  __syncthreads();
  const float m = fmaxf(fmaxf(wred[0], wred[1]), fmaxf(wred[2], wred[3]));
  const float scale = fmaxf(m / qmax, 1e-8f);
  const float inv = 1.0f / scale;
  if (t == 0) scales[row] = scale;
  int* qo = (int*)(q + (size_t)row * HDIM);
#pragma unroll
  for (int i = 0; i < 4; ++i) {
    const int b0 = (int)fminf(fmaxf(rintf(v[i].x * inv), clipLo), qmax);
    const int b1 = (int)fminf(fmaxf(rintf(v[i].y * inv), clipLo), qmax);
    const int b2 = (int)fminf(fmaxf(rintf(v[i].z * inv), clipLo), qmax);
    const int b3 = (int)fminf(fmaxf(rintf(v[i].w * inv), clipLo), qmax);
    qo[t + 256 * i] = (b0 & 0xff) | ((b1 & 0xff) << 8) | ((b2 & 0xff) << 16) | ((b3 & 0xff) << 24);
  }
}

// ======== i8 MFMA GEMM, 128x128 tile, 4 waves, 2-phase dbuf, fused epilogue ========
// MODE 0: C write (f32).  MODE 1: rope + per-(token,head) quant8 -> o8/oscale.
// MODE 2: per-(token,head) quant + fold scale + transposed bf16 -> vqT.
template<int MODE>
__global__ __launch_bounds__(256, 2) void gemm_i8_fused_kernel(
    const int8_t* __restrict__ A, const float* __restrict__ sa,
    const int8_t* __restrict__ Bw, const float* __restrict__ sb,
    float* __restrict__ C,
    int8_t* __restrict__ o8, float* __restrict__ oscale,
    const float* __restrict__ ctab, const float* __restrict__ stab,
    unsigned short* __restrict__ vqT)
{
  __shared__ __align__(16) char smem[128 * 129 * 4];   // 66048 B (dbuf 64KB aliased)
  __shared__ float vscale[128];
  __shared__ float vinv[128];
  int8_t (*asB)[128 * 128] = (int8_t(*)[128 * 128])smem;
  int8_t (*bsB)[128 * 128] = (int8_t(*)[128 * 128])(smem + 32768);
  float (*fx)[129] = (float(*)[129])smem;

  const int flat = blockIdx.y * gridDim.x + blockIdx.x;
  const int nf = (flat & 7) * 64 + (flat >> 3);
  const int bmi = nf & 15, bni = nf >> 4;
  const int bm = bmi * 128, bn = bni * 128;

  const int tid = threadIdx.x;
  const int w = tid >> 6, l = tid & 63;
  const int l15 = l & 15, lg = l >> 4, l7 = l & 7;
  const int lr = l >> 3, g7 = l & 7;
  const int m0 = (w >> 1) * 64, n0 = (w & 1) * 64;

  const int8_t* aT = A + (size_t)(bm + lr) * HDIM + ((g7 ^ lr) << 4);
  const int8_t* bT = Bw + (size_t)(bn + lr) * HDIM + ((g7 ^ lr) << 4);

  i32x4 acc[4][4];
#pragma unroll
  for (int i = 0; i < 4; ++i)
#pragma unroll
    for (int j = 0; j < 4; ++j) acc[i][j] = (i32x4){0, 0, 0, 0};

  auto stage = [&](int t) {
    const int bf = t & 1;
    const size_t k = (size_t)t * 128;
#pragma unroll
    for (int i = 0; i < 4; ++i) {
      const int r0 = w * 32 + i * 8;
      gl2lds16(aT + (size_t)r0 * HDIM + k, asB[bf] + r0 * 128);
      gl2lds16(bT + (size_t)r0 * HDIM + k, bsB[bf] + r0 * 128);
    }
  };

  stage(0);
  asm volatile("s_waitcnt vmcnt(0)" ::: "memory");
  __builtin_amdgcn_s_barrier();

  for (int t = 0; t < 32; ++t) {
    if (t < 31) stage(t + 1);
    const int cur = t & 1;
    __builtin_amdgcn_s_setprio(1);
#pragma unroll
    for (int kk = 0; kk < 2; ++kk) {
      i32x4 aF[4], bF[4];
      const int slot = (((kk << 2) + lg) ^ l7) << 4;
#pragma unroll
      for (int i = 0; i < 4; ++i)
        aF[i] = *(const i32x4*)(asB[cur] + (m0 + i * 16 + l15) * 128 + slot);
#pragma unroll
      for (int j = 0; j < 4; ++j)
        bF[j] = *(const i32x4*)(bsB[cur] + (n0 + j * 16 + l15) * 128 + slot);
#pragma unroll
      for (int i = 0; i < 4; ++i)
#pragma unroll
        for (int j = 0; j < 4; ++j)
          acc[i][j] = __builtin_amdgcn_mfma_i32_16x16x64_i8(aF[i], bF[j], acc[i][j], 0, 0, 0);
    }
    __builtin_amdgcn_s_setprio(0);
    if (t < 31) {
      asm volatile("s_waitcnt vmcnt(0)" ::: "memory");
      __builtin_amdgcn_s_barrier();
    }
  }

  float sbr[4];
#pragma unroll
  for (int j = 0; j < 4; ++j) sbr[j] = sb[bn + n0 + j * 16 + l15];

  if (MODE == 0) {
#pragma unroll
    for (int i = 0; i < 4; ++i) {
#pragma unroll
      for (int r = 0; r < 4; ++r) {
        const int m = bm + m0 + i * 16 + lg * 4 + r;
        const float sm = sa[m];
        float* cp = C + (size_t)m * HDIM + bn + n0 + l15;
#pragma unroll
        for (int j = 0; j < 4; ++j)
          cp[j * 16] = sm * sbr[j] * (float)acc[i][j][r];
      }
    }
    return;
  }

  // ---- scatter scaled f32 tile to LDS ----
  __syncthreads();
#pragma unroll
  for (int i = 0; i < 4; ++i) {
#pragma unroll
    for (int r = 0; r < 4; ++r) {
      const int ml = m0 + i * 16 + lg * 4 + r;
      const float sm = sa[bm + ml];
#pragma unroll
      for (int j = 0; j < 4; ++j)
        fx[ml][n0 + j * 16 + l15] = sm * sbr[j] * (float)acc[i][j][r];
    }
  }
  __syncthreads();

  const int h = bn >> 7;   // one head per block (BN == DHEAD)

  if (MODE == 1) {
    const int row = tid >> 1, half = tid & 1;
    const int sg = bm + row;
    const int b = sg >> 10, s = sg & (S_LEN - 1);
    const float* ct = ctab + (size_t)s * 64;
    const float* st = stab + (size_t)s * 64;
    float am = 0.f;
#pragma unroll
    for (int d0 = 0; d0 < 64; ++d0) {
      const int d = half * 64 + d0;
      const float x0 = fx[row][d];
      const float x1 = fx[row][d ^ 64];
      const float c = ct[d0], sn = st[d0];
      const float v = half ? (x0 * c + x1 * sn) : (x0 * c - x1 * sn);
      fx[row][d] = v;
      am = fmaxf(am, fabsf(v));
    }
    am = fmaxf(am, __shfl_xor(am, 1));
    const float scale = fmaxf(am * (1.0f / 127.0f), 1e-8f);
    const float inv = 1.0f / scale;
    int8_t* op = o8 + (((size_t)(b * NHEAD + h)) * S_LEN + s) * DHEAD + half * 64;
#pragma unroll
    for (int c4 = 0; c4 < 4; ++c4) {
      i32x4 dw;
#pragma unroll
      for (int u = 0; u < 4; ++u) {
        int pk = 0;
#pragma unroll
        for (int bi = 0; bi < 4; ++bi) {
          const float v = fx[row][half * 64 + c4 * 16 + u * 4 + bi];
          const int q = (int)fminf(fmaxf(rintf(v * inv), -128.f), 127.f);
          pk |= (q & 0xff) << (8 * bi);
        }
        dw[u] = pk;
      }
      *(i32x4*)(op + c4 * 16) = dw;
    }
    if (!half) oscale[((size_t)(b * NHEAD + h)) * S_LEN + s] = scale;
  } else {
    {
      const int row = tid >> 1, half = tid & 1;
      float am = 0.f;
#pragma unroll
      for (int d0 = 0; d0 < 64; ++d0)
        am = fmaxf(am, fabsf(fx[row][half * 64 + d0]));
      am = fmaxf(am, __shfl_xor(am, 1));
      if (!half) {
        const float s = fmaxf(am * (1.0f / 127.0f), 1e-8f);
        vscale[row] = s;
        vinv[row] = 1.0f / s;
      }
    }
    __syncthreads();
    {
      const int d = tid >> 1, sh = tid & 1;
      const int b = bm >> 10;
      const int bh = b * NHEAD + h;
      unsigned short* op = vqT + ((size_t)bh * DHEAD + d) * S_LEN + (bm & (S_LEN - 1)) + sh * 64;
#pragma unroll
      for (int c8 = 0; c8 < 8; ++c8) {
        i32x4 dw;
#pragma unroll
        for (int u = 0; u < 4; ++u) {
          const int sl = sh * 64 + c8 * 8 + u * 2;
          const float sc0 = vscale[sl], sc1 = vscale[sl + 1];
          const float q0 = fminf(fmaxf(rintf(fx[sl][d] * vinv[sl]), -128.f), 127.f);
          const float q1 = fminf(fmaxf(rintf(fx[sl + 1][d] * vinv[sl + 1]), -128.f), 127.f);
          dw[u] = (int)f2bf(q0 * sc0) | ((int)f2bf(q1 * sc1) << 16);
        }
        *(i32x4*)(op + c8 * 8) = dw;
      }
    }
  }
}

// -------- single-pass online attn, K/V double-buffered, defer-max --------
#define QB 64
#define KB 64

__global__ __launch_bounds__(256) void attn_mfma_kernel(
    const int8_t* __restrict__ qq, const float* __restrict__ sq,
    const int8_t* __restrict__ kq, const float* __restrict__ sk,
    const unsigned short* __restrict__ vqT,   // bf16 bits, sv pre-folded
    float* __restrict__ attn)
{
  __shared__ __align__(16) int8_t ks[2][KB * 128];
  __shared__ __align__(16) unsigned short vs[2][128 * 64];
  __shared__ __align__(16) unsigned short ps[QB][64];

  const int tid = threadIdx.x;
  const int w = tid >> 6;
  const int l = tid & 63;
  const int l15 = l & 15;
  const int lg = l >> 4;
  const int lr = l >> 3, g7 = l & 7;
  const int bflat = blockIdx.x;
  const int bh = (bflat & 7) + 8 * (bflat >> 6);
  const int qxb = (bflat >> 3) & 7;
  const size_t bhS = (size_t)bh * S_LEN;
  const int b = bh >> 5, h = bh & 31;
  const int NT = S_LEN / QB;

  auto stageKV = [&](int kt, int nb) {
    const int k0 = kt * KB;
#pragma unroll
    for (int i = 0; i < 2; ++i) {
      const int r0 = w * 16 + i * 8;
      gl2lds16(kq + (bhS + k0 + r0 + lr) * (size_t)128 + ((g7 ^ lr) << 4),
               ks[nb] + r0 * 128);
    }
#pragma unroll
    for (int i = 0; i < 4; ++i) {
      const int r0 = w * 32 + i * 8;
      gl2lds16(vqT + ((size_t)bh * 128 + r0 + lr) * S_LEN + k0 + ((g7 ^ lr) << 3),
               vs[nb] + r0 * 64);
    }
  };

  for (int rep = 0; rep < 2; ++rep) {
    const int qt = rep ? (NT - 1 - qxb) : qxb;
    const int q0 = qt * QB;
    const int nkt = qt + 1;

    const int qrow = q0 + w * 16 + l15;
    const int8_t* qp = qq + (bhS + qrow) * (size_t)DHEAD;
    const i32x4 qa0 = *(const i32x4*)(qp + lg * 16);
    const i32x4 qa1 = *(const i32x4*)(qp + 64 + lg * 16);

    float sqv[4];
    int qg[4];
#pragma unroll
    for (int r = 0; r < 4; ++r) {
      qg[r] = q0 + w * 16 + lg * 4 + r;
      sqv[r] = sq[bhS + qg[r]] * 0.08838834764831843f * 1.4426950408889634f;
    }

    float m_run[4] = {-3.0e38f, -3.0e38f, -3.0e38f, -3.0e38f};
    float rs[4] = {0.f, 0.f, 0.f, 0.f};
    f32x4 oacc[8];
#pragma unroll
    for (int ds = 0; ds < 8; ++ds) oacc[ds] = (f32x4){0.f, 0.f, 0.f, 0.f};

    const int qloc = w * 16 + l15;
    const int swA0 = (lg ^ (qloc & 7)) << 3;
    const int swA1 = ((lg + 4) ^ (qloc & 7)) << 3;

    stageKV(0, 0);
    float skn[4];
#pragma unroll
    for (int c = 0; c < 4; ++c) skn[c] = sk[bhS + c * 16 + l15];
    asm volatile("s_waitcnt vmcnt(0)" ::: "memory");
    __builtin_amdgcn_s_barrier();

    int nb = 0;
    for (int kt = 0; kt < nkt; ++kt) {
      const int k0 = kt * KB;
      float skc[4];
#pragma unroll
      for (int c = 0; c < 4; ++c) skc[c] = skn[c];
      if (kt + 1 < nkt) {
        stageKV(kt + 1, nb ^ 1);
#pragma unroll
        for (int c = 0; c < 4; ++c)
          skn[c] = sk[bhS + (kt + 1) * KB + c * 16 + l15];
      }
      const bool diag = (kt == nkt - 1);

      float s2v[4][4];
      float tmax[4] = {-3.0e38f, -3.0e38f, -3.0e38f, -3.0e38f};
      __builtin_amdgcn_s_setprio(1);
#pragma unroll
      for (int c = 0; c < 4; ++c) {
        const int krow = c * 16 + l15;
        const i32x4 b0 = *(const i32x4*)(ks[nb] + krow * 128 + ((lg ^ (krow & 7)) << 4));
        const i32x4 b1 = *(const i32x4*)(ks[nb] + krow * 128 + (((lg + 4) ^ (krow & 7)) << 4));
        i32x4 acc = {0, 0, 0, 0};
        acc = __builtin_amdgcn_mfma_i32_16x16x64_i8(qa0, b0, acc, 0, 0, 0);
        acc = __builtin_amdgcn_mfma_i32_16x16x64_i8(qa1, b1, acc, 0, 0, 0);
        const int kgl = k0 + krow;
#pragma unroll
        for (int r = 0; r < 4; ++r) {
          const bool valid = !diag || (kgl <= qg[r]);
          const float s2 = valid ? ((float)acc[r] * sqv[r] * skc[c]) : -3.0e38f;
          s2v[c][r] = s2;
          tmax[r] = fmaxf(tmax[r], s2);
        }
      }
      __builtin_amdgcn_s_setprio(0);
#pragma unroll
      for (int r = 0; r < 4; ++r)
#pragma unroll
        for (int off = 1; off < 16; off <<= 1)
          tmax[r] = fmaxf(tmax[r], __shfl_xor(tmax[r], off));

#pragma unroll
      for (int r = 0; r < 4; ++r) {
        if (tmax[r] > m_run[r] + 8.0f) {
          const float f = exp2f(m_run[r] - tmax[r]);
          m_run[r] = tmax[r];
          rs[r] *= f;
#pragma unroll
          for (int ds = 0; ds < 8; ++ds) oacc[ds][r] *= f;
        }
      }

#pragma unroll
      for (int c = 0; c < 4; ++c) {
        const int krow = c * 16 + l15;
#pragma unroll
        for (int r = 0; r < 4; ++r) {
          const float e = exp2f(s2v[c][r] - m_run[r]);
          rs[r] += e;
          const float p = rintf(e * 127.0f);
          const int qr = w * 16 + lg * 4 + r;
          const int sidx = (((krow >> 3) ^ (qr & 7)) << 3) | (krow & 7);
          ps[qr][sidx] = f2bf(p);
        }
      }

      const bf16x8 a0 = *(const bf16x8*)&ps[qloc][swA0];
      const bf16x8 a1 = *(const bf16x8*)&ps[qloc][swA1];
      __builtin_amdgcn_s_setprio(1);
#pragma unroll
      for (int ds = 0; ds < 8; ++ds) {
        const int d = ds * 16 + l15;
        const bf16x8 bv0 = *(const bf16x8*)(vs[nb] + d * 64 + ((lg ^ (d & 7)) << 3));
        const bf16x8 bv1 = *(const bf16x8*)(vs[nb] + d * 64 + (((lg + 4) ^ (d & 7)) << 3));
        oacc[ds] = __builtin_amdgcn_mfma_f32_16x16x32_bf16(a0, bv0, oacc[ds], 0, 0, 0);
        oacc[ds] = __builtin_amdgcn_mfma_f32_16x16x32_bf16(a1, bv1, oacc[ds], 0, 0, 0);
      }
      __builtin_amdgcn_s_setprio(0);
      asm volatile("s_waitcnt vmcnt(0)" ::: "memory");
      __builtin_amdgcn_s_barrier();
      nb ^= 1;
    }

#pragma unroll
    for (int r = 0; r < 4; ++r)
#pragma unroll
      for (int off = 1; off < 16; off <<= 1)
        rs[r] += __shfl_xor(rs[r], off);

#pragma unroll
    for (int r = 0; r < 4; ++r) {
      const float inv = 1.0f / (127.0f * rs[r]);
      float* op = attn + ((size_t)(b * S_LEN + qg[r])) * HDIM + h * DHEAD + l15;
#pragma unroll
      for (int ds = 0; ds < 8; ++ds)
        op[ds * 16] = oacc[ds][r] * inv;
    }
  }
}

extern "C" void kernel_launch(void* const* d_in, const int* in_sizes, int n_in,
                              void* d_out, int out_size, void* d_ws, size_t ws_size,
                              hipStream_t stream) {
  const float* hs = (const float*)d_in[0];
  const float* wmat[4] = { (const float*)d_in[1], (const float*)d_in[2],
                           (const float*)d_in[3], (const float*)d_in[4] };

  char* p = (char*)d_ws;
  auto take = [&](size_t sz) { char* r = p; p += (sz + 255) & ~(size_t)255; return r; };

  int8_t* xq8 = (int8_t*)take((size_t)MTOK * HDIM);
  int8_t* w4[4];
  for (int i = 0; i < 4; ++i) w4[i] = (int8_t*)take((size_t)HDIM * HDIM);
  float* sx = (float*)take((size_t)MTOK * 4);
  float* sw[4];
  for (int i = 0; i < 4; ++i) sw[i] = (float*)take((size_t)HDIM * 4);
  float* y = (float*)take((size_t)MTOK * HDIM * 4);
  int8_t* qq8 = (int8_t*)take((size_t)MTOK * HDIM);
  int8_t* kq8 = (int8_t*)take((size_t)MTOK * HDIM);
  unsigned short* vqT = (unsigned short*)take((size_t)MTOK * HDIM * 2);
  float* sqs = (float*)take((size_t)BATCH * NHEAD * S_LEN * 4);
  float* sks = (float*)take((size_t)BATCH * NHEAD * S_LEN * 4);
  float* sattn = (float*)take((size_t)MTOK * 4);
  float* ctab = (float*)take((size_t)S_LEN * 64 * 4);
  float* stab = (float*)take((size_t)S_LEN * 64 * 4);

  prequant_kernel<<<MTOK + 4 * HDIM + 256, 256, 0, stream>>>(
      hs, wmat[0], wmat[1], wmat[2], wmat[3],
      xq8, w4[0], w4[1], w4[2], w4[3],
      sx, sw[0], sw[1], sw[2], sw[3], ctab, stab);

  const dim3 gg(HDIM / 128, MTOK / 128);  // 512 blocks
  gemm_i8_fused_kernel<1><<<gg, 256, 0, stream>>>(
      xq8, sx, w4[0], sw[0], nullptr, qq8, sqs, ctab, stab, nullptr);
  gemm_i8_fused_kernel<1><<<gg, 256, 0, stream>>>(
      xq8, sx, w4[1], sw[1], nullptr, kq8, sks, ctab, stab, nullptr);
  gemm_i8_fused_kernel<2><<<gg, 256, 0, stream>>>(
      xq8, sx, w4[2], sw[2], nullptr, nullptr, nullptr, nullptr, nullptr, vqT);

  attn_mfma_kernel<<<512, 256, 0, stream>>>(qq8, sqs, kq8, sks, vqT, y);

  rowquant_kernel<<<MTOK, 256, 0, stream>>>(y, xq8, sattn, 127.f, -128.f);
  gemm_i8_fused_kernel<0><<<gg, 256, 0, stream>>>(
      xq8, sattn, w4[3], sw[3], (float*)d_out, nullptr, nullptr, nullptr, nullptr, nullptr);
}

// Round 17
// 286.114 us; speedup vs baseline: 1.0888x; 1.0251x over previous
//
#include <hip/hip_runtime.h>
#include <stdint.h>

#define S_LEN 1024
#define HDIM  4096
#define NHEAD 32
#define DHEAD 128
#define BATCH 2
#define MTOK  (BATCH * S_LEN)   // 2048

typedef __attribute__((ext_vector_type(4))) int   i32x4;
typedef __attribute__((ext_vector_type(4))) float f32x4;
typedef __attribute__((ext_vector_type(8))) short bf16x8;

#define GLOBAL_AS __attribute__((address_space(1)))
#define LDS_AS    __attribute__((address_space(3)))

__device__ __forceinline__ void gl2lds16(const void* g, void* l) {
  __builtin_amdgcn_global_load_lds((const GLOBAL_AS unsigned int*)(g),
                                   (LDS_AS unsigned int*)(l), 16, 0, 0);
}

// float -> bf16 bits, round-to-nearest-even
__device__ __forceinline__ unsigned short f2bf(float f) {
  unsigned int u = __float_as_uint(f);
  unsigned int r = (u + 0x7fffu + ((u >> 16) & 1u)) >> 16;
  return (unsigned short)r;
}

#define PIN4(v) asm volatile("" : "+v"(v.x), "+v"(v.y), "+v"(v.z), "+v"(v.w))

// non-temporal float4 load (read-once streams: keep out of caches)
__device__ __forceinline__ float4 ld_nt4(const float4* p) {
  const f32x4 t = __builtin_nontemporal_load((const f32x4*)p);
  float4 r; r.x = t[0]; r.y = t[1]; r.z = t[2]; r.w = t[3];
  return r;
}

// -------- merged input fake-quant + rope-table build (extra 256 blocks) --------
__global__ __launch_bounds__(256) void prequant_kernel(
    const float* __restrict__ hs,
    const float* __restrict__ w0, const float* __restrict__ w1,
    const float* __restrict__ w2, const float* __restrict__ w3,
    int8_t* __restrict__ xq8,
    int8_t* __restrict__ q0, int8_t* __restrict__ q1,
    int8_t* __restrict__ q2, int8_t* __restrict__ q3,
    float* __restrict__ sx,
    float* __restrict__ s0, float* __restrict__ s1,
    float* __restrict__ s2, float* __restrict__ s3,
    float* __restrict__ ctab, float* __restrict__ stab)
{
  const int row = blockIdx.x;
  if (row >= MTOK + 4 * HDIM) {
    const int t = (row - (MTOK + 4 * HDIM)) * 256 + threadIdx.x;
    const int s = t >> 6, d = t & 63;
    const float inv = powf(10000.0f, -(float)d * (1.0f / 64.0f));
    const float ang = (float)s * inv;
    float sn, c;
    sincosf(ang, &sn, &c);
    ctab[t] = c;
    stab[t] = sn;
    return;
  }
  const float* src; int8_t* dst; float* sc; float qmax, clipLo; int lrow;
  if (row < MTOK) {
    src = hs; dst = xq8; sc = sx; qmax = 127.f; clipLo = -128.f; lrow = row;
  } else {
    const int wi = (row - MTOK) >> 12;
    lrow = (row - MTOK) & 4095;
    qmax = 7.f; clipLo = -8.f;
    src = (wi == 0) ? w0 : (wi == 1) ? w1 : (wi == 2) ? w2 : w3;
    dst = (wi == 0) ? q0 : (wi == 1) ? q1 : (wi == 2) ? q2 : q3;
    sc  = (wi == 0) ? s0 : (wi == 1) ? s1 : (wi == 2) ? s2 : s3;
  }
  const int t = threadIdx.x;
  const float4* xr = (const float4*)(src + (size_t)lrow * HDIM);
  float4 v[4];
  float am = 0.f;
#pragma unroll
  for (int i = 0; i < 4; ++i) {
    v[i] = ld_nt4(xr + t + 256 * i);          // non-temporal: read-once stream
    am = fmaxf(am, fmaxf(fmaxf(fabsf(v[i].x), fabsf(v[i].y)),
                         fmaxf(fabsf(v[i].z), fabsf(v[i].w))));
  }
#pragma unroll
  for (int i = 0; i < 4; ++i) PIN4(v[i]);
#pragma unroll
  for (int off = 32; off > 0; off >>= 1) am = fmaxf(am, __shfl_down(am, off));
  __shared__ float wred[4];
  if ((t & 63) == 0) wred[t >> 6] = am;
  __syncthreads();
  const float m = fmaxf(fmaxf(wred[0], wred[1]), fmaxf(wred[2], wred[3]));
  const float scale = fmaxf(m / qmax, 1e-8f);
  const float inv = 1.0f / scale;
  if (t == 0) sc[lrow] = scale;
  int* qo = (int*)(dst + (size_t)lrow * HDIM);
#pragma unroll
  for (int i = 0; i < 4; ++i) {
    const int b0 = (int)fminf(fmaxf(rintf(v[i].x * inv), clipLo), qmax);
    const int b1 = (int)fminf(fmaxf(rintf(v[i].y * inv), clipLo), qmax);
    const int b2 = (int)fminf(fmaxf(rintf(v[i].z * inv), clipLo), qmax);
    const int b3 = (int)fminf(fmaxf(rintf(v[i].w * inv), clipLo), qmax);
    qo[t + 256 * i] = (b0 & 0xff) | ((b1 & 0xff) << 8) | ((b2 & 0xff) << 16) | ((b3 & 0xff) << 24);
  }
}

// -------- per-row fake-quant for attn output --------
__global__ __launch_bounds__(256) void rowquant_kernel(
    const float* __restrict__ x, int8_t* __restrict__ q,
    float* __restrict__ scales, float qmax, float clipLo)
{
  const int row = blockIdx.x;
  const int t = threadIdx.x;
  const float4* xr = (const float4*)(x + (size_t)row * HDIM);
  float4 v[4];
  float am = 0.f;
#pragma unroll
  for (int i = 0; i < 4; ++i) {
    v[i] = ld_nt4(xr + t + 256 * i);
    am = fmaxf(am, fmaxf(fmaxf(fabsf(v[i].x), fabsf(v[i].y)),
                         fmaxf(fabsf(v[i].z), fabsf(v[i].w))));
  }
#pragma unroll
  for (int i = 0; i < 4; ++i) PIN4(v[i]);
#pragma unroll
  for (int off = 32; off > 0; off >>= 1) am = fmaxf(am, __shfl_down(am, off));
  __shared__ float wred[4];
  if ((t & 63) == 0) wred[t >> 6] = am;
  __syncthreads();
  const float m = fmaxf(fmaxf(wred[0], wred[1]), fmaxf(wred[2], wred[3]));
  const float scale = fmaxf(m / qmax, 1e-8f);
  const float inv = 1.0f / scale;
  if (t == 0) scales[row] = scale;
  int* qo = (int*)(q + (size_t)row * HDIM);
#pragma unroll
  for (int i = 0; i < 4; ++i) {
    const int b0 = (int)fminf(fmaxf(rintf(v[i].x * inv), clipLo), qmax);
    const int b1 = (int)fminf(fmaxf(rintf(v[i].y * inv), clipLo), qmax);
    const int b2 = (int)fminf(fmaxf(rintf(v[i].z * inv), clipLo), qmax);
    const int b3 = (int)fminf(fmaxf(rintf(v[i].w * inv), clipLo), qmax);
    qo[t + 256 * i] = (b0 & 0xff) | ((b1 & 0xff) << 8) | ((b2 & 0xff) << 16) | ((b3 & 0xff) << 24);
  }
}

// ======== i8 MFMA GEMM, 128x128 tile, 4 waves, 2-phase dbuf, fused epilogue ========
// MODE 0: C write (f32).  MODE 1: rope + per-(token,head) quant8 -> o8/oscale.
// MODE 2: per-(token,head) quant + fold scale + transposed bf16 -> vqT.
template<int MODE>
__global__ __launch_bounds__(256, 2) void gemm_i8_fused_kernel(
    const int8_t* __restrict__ A, const float* __restrict__ sa,
    const int8_t* __restrict__ Bw, const float* __restrict__ sb,
    float* __restrict__ C,
    int8_t* __restrict__ o8, float* __restrict__ oscale,
    const float* __restrict__ ctab, const float* __restrict__ stab,
    unsigned short* __restrict__ vqT)
{
  __shared__ __align__(16) char smem[128 * 129 * 4];   // 66048 B (dbuf 64KB aliased)
  __shared__ float vscale[128];
  __shared__ float vinv[128];
  int8_t (*asB)[128 * 128] = (int8_t(*)[128 * 128])smem;
  int8_t (*bsB)[128 * 128] = (int8_t(*)[128 * 128])(smem + 32768);
  float (*fx)[129] = (float(*)[129])smem;

  const int flat = blockIdx.y * gridDim.x + blockIdx.x;
  const int nf = (flat & 7) * 64 + (flat >> 3);
  const int bmi = nf & 15, bni = nf >> 4;
  const int bm = bmi * 128, bn = bni * 128;

  const int tid = threadIdx.x;
  const int w = tid >> 6, l = tid & 63;
  const int l15 = l & 15, lg = l >> 4, l7 = l & 7;
  const int lr = l >> 3, g7 = l & 7;
  const int m0 = (w >> 1) * 64, n0 = (w & 1) * 64;

  const int8_t* aT = A + (size_t)(bm + lr) * HDIM + ((g7 ^ lr) << 4);
  const int8_t* bT = Bw + (size_t)(bn + lr) * HDIM + ((g7 ^ lr) << 4);

  i32x4 acc[4][4];
#pragma unroll
  for (int i = 0; i < 4; ++i)
#pragma unroll
    for (int j = 0; j < 4; ++j) acc[i][j] = (i32x4){0, 0, 0, 0};

  auto stage = [&](int t) {
    const int bf = t & 1;
    const size_t k = (size_t)t * 128;
#pragma unroll
    for (int i = 0; i < 4; ++i) {
      const int r0 = w * 32 + i * 8;
      gl2lds16(aT + (size_t)r0 * HDIM + k, asB[bf] + r0 * 128);
      gl2lds16(bT + (size_t)r0 * HDIM + k, bsB[bf] + r0 * 128);
    }
  };

  stage(0);
  asm volatile("s_waitcnt vmcnt(0)" ::: "memory");
  __builtin_amdgcn_s_barrier();

  for (int t = 0; t < 32; ++t) {
    if (t < 31) stage(t + 1);
    const int cur = t & 1;
    __builtin_amdgcn_s_setprio(1);
#pragma unroll
    for (int kk = 0; kk < 2; ++kk) {
      i32x4 aF[4], bF[4];
      const int slot = (((kk << 2) + lg) ^ l7) << 4;
#pragma unroll
      for (int i = 0; i < 4; ++i)
        aF[i] = *(const i32x4*)(asB[cur] + (m0 + i * 16 + l15) * 128 + slot);
#pragma unroll
      for (int j = 0; j < 4; ++j)
        bF[j] = *(const i32x4*)(bsB[cur] + (n0 + j * 16 + l15) * 128 + slot);
#pragma unroll
      for (int i = 0; i < 4; ++i)
#pragma unroll
        for (int j = 0; j < 4; ++j)
          acc[i][j] = __builtin_amdgcn_mfma_i32_16x16x64_i8(aF[i], bF[j], acc[i][j], 0, 0, 0);
    }
    __builtin_amdgcn_s_setprio(0);
    if (t < 31) {
      asm volatile("s_waitcnt vmcnt(0)" ::: "memory");
      __builtin_amdgcn_s_barrier();
    }
  }

  float sbr[4];
#pragma unroll
  for (int j = 0; j < 4; ++j) sbr[j] = sb[bn + n0 + j * 16 + l15];

  if (MODE == 0) {
#pragma unroll
    for (int i = 0; i < 4; ++i) {
#pragma unroll
      for (int r = 0; r < 4; ++r) {
        const int m = bm + m0 + i * 16 + lg * 4 + r;
        const float sm = sa[m];
        float* cp = C + (size_t)m * HDIM + bn + n0 + l15;
#pragma unroll
        for (int j = 0; j < 4; ++j)
          cp[j * 16] = sm * sbr[j] * (float)acc[i][j][r];
      }
    }
    return;
  }

  // ---- scatter scaled f32 tile to LDS ----
  __syncthreads();
#pragma unroll
  for (int i = 0; i < 4; ++i) {
#pragma unroll
    for (int r = 0; r < 4; ++r) {
      const int ml = m0 + i * 16 + lg * 4 + r;
      const float sm = sa[bm + ml];
#pragma unroll
      for (int j = 0; j < 4; ++j)
        fx[ml][n0 + j * 16 + l15] = sm * sbr[j] * (float)acc[i][j][r];
    }
  }
  __syncthreads();

  const int h = bn >> 7;   // one head per block (BN == DHEAD)

  if (MODE == 1) {
    const int row = tid >> 1, half = tid & 1;
    const int sg = bm + row;
    const int b = sg >> 10, s = sg & (S_LEN - 1);
    const float* ct = ctab + (size_t)s * 64;
    const float* st = stab + (size_t)s * 64;
    float am = 0.f;
#pragma unroll
    for (int d0 = 0; d0 < 64; ++d0) {
      const int d = half * 64 + d0;
      const float x0 = fx[row][d];
      const float x1 = fx[row][d ^ 64];
      const float c = ct[d0], sn = st[d0];
      const float v = half ? (x0 * c + x1 * sn) : (x0 * c - x1 * sn);
      fx[row][d] = v;
      am = fmaxf(am, fabsf(v));
    }
    am = fmaxf(am, __shfl_xor(am, 1));
    const float scale = fmaxf(am * (1.0f / 127.0f), 1e-8f);
    const float inv = 1.0f / scale;
    int8_t* op = o8 + (((size_t)(b * NHEAD + h)) * S_LEN + s) * DHEAD + half * 64;
#pragma unroll
    for (int c4 = 0; c4 < 4; ++c4) {
      i32x4 dw;
#pragma unroll
      for (int u = 0; u < 4; ++u) {
        int pk = 0;
#pragma unroll
        for (int bi = 0; bi < 4; ++bi) {
          const float v = fx[row][half * 64 + c4 * 16 + u * 4 + bi];
          const int q = (int)fminf(fmaxf(rintf(v * inv), -128.f), 127.f);
          pk |= (q & 0xff) << (8 * bi);
        }
        dw[u] = pk;
      }
      *(i32x4*)(op + c4 * 16) = dw;
    }
    if (!half) oscale[((size_t)(b * NHEAD + h)) * S_LEN + s] = scale;
  } else {
    {
      const int row = tid >> 1, half = tid & 1;
      float am = 0.f;
#pragma unroll
      for (int d0 = 0; d0 < 64; ++d0)
        am = fmaxf(am, fabsf(fx[row][half * 64 + d0]));
      am = fmaxf(am, __shfl_xor(am, 1));
      if (!half) {
        const float s = fmaxf(am * (1.0f / 127.0f), 1e-8f);
        vscale[row] = s;
        vinv[row] = 1.0f / s;
      }
    }
    __syncthreads();
    {
      const int d = tid >> 1, sh = tid & 1;
      const int b = bm >> 10;
      const int bh = b * NHEAD + h;
      unsigned short* op = vqT + ((size_t)bh * DHEAD + d) * S_LEN + (bm & (S_LEN - 1)) + sh * 64;
#pragma unroll
      for (int c8 = 0; c8 < 8; ++c8) {
        i32x4 dw;
#pragma unroll
        for (int u = 0; u < 4; ++u) {
          const int sl = sh * 64 + c8 * 8 + u * 2;
          const float sc0 = vscale[sl], sc1 = vscale[sl + 1];
          const float q0 = fminf(fmaxf(rintf(fx[sl][d] * vinv[sl]), -128.f), 127.f);
          const float q1 = fminf(fmaxf(rintf(fx[sl + 1][d] * vinv[sl + 1]), -128.f), 127.f);
          dw[u] = (int)f2bf(q0 * sc0) | ((int)f2bf(q1 * sc1) << 16);
        }
        *(i32x4*)(op + c8 * 8) = dw;
      }
    }
  }
}

// -------- single-pass online attn, K/V double-buffered, defer-max --------
#define QB 64
#define KB 64

__global__ __launch_bounds__(256) void attn_mfma_kernel(
    const int8_t* __restrict__ qq, const float* __restrict__ sq,
    const int8_t* __restrict__ kq, const float* __restrict__ sk,
    const unsigned short* __restrict__ vqT,   // bf16 bits, sv pre-folded
    float* __restrict__ attn)
{
  __shared__ __align__(16) int8_t ks[2][KB * 128];
  __shared__ __align__(16) unsigned short vs[2][128 * 64];
  __shared__ __align__(16) unsigned short ps[QB][64];

  const int tid = threadIdx.x;
  const int w = tid >> 6;
  const int l = tid & 63;
  const int l15 = l & 15;
  const int lg = l >> 4;
  const int lr = l >> 3, g7 = l & 7;
  const int bflat = blockIdx.x;
  const int bh = (bflat & 7) + 8 * (bflat >> 6);
  const int qxb = (bflat >> 3) & 7;
  const size_t bhS = (size_t)bh * S_LEN;
  const int b = bh >> 5, h = bh & 31;
  const int NT = S_LEN / QB;

  auto stageKV = [&](int kt, int nb) {
    const int k0 = kt * KB;
#pragma unroll
    for (int i = 0; i < 2; ++i) {
      const int r0 = w * 16 + i * 8;
      gl2lds16(kq + (bhS + k0 + r0 + lr) * (size_t)128 + ((g7 ^ lr) << 4),
               ks[nb] + r0 * 128);
    }
#pragma unroll
    for (int i = 0; i < 4; ++i) {
      const int r0 = w * 32 + i * 8;
      gl2lds16(vqT + ((size_t)bh * 128 + r0 + lr) * S_LEN + k0 + ((g7 ^ lr) << 3),
               vs[nb] + r0 * 64);
    }
  };

  for (int rep = 0; rep < 2; ++rep) {
    const int qt = rep ? (NT - 1 - qxb) : qxb;
    const int q0 = qt * QB;
    const int nkt = qt + 1;

    const int qrow = q0 + w * 16 + l15;
    const int8_t* qp = qq + (bhS + qrow) * (size_t)DHEAD;
    const i32x4 qa0 = *(const i32x4*)(qp + lg * 16);
    const i32x4 qa1 = *(const i32x4*)(qp + 64 + lg * 16);

    float sqv[4];
    int qg[4];
#pragma unroll
    for (int r = 0; r < 4; ++r) {
      qg[r] = q0 + w * 16 + lg * 4 + r;
      sqv[r] = sq[bhS + qg[r]] * 0.08838834764831843f * 1.4426950408889634f;
    }

    float m_run[4] = {-3.0e38f, -3.0e38f, -3.0e38f, -3.0e38f};
    float rs[4] = {0.f, 0.f, 0.f, 0.f};
    f32x4 oacc[8];
#pragma unroll
    for (int ds = 0; ds < 8; ++ds) oacc[ds] = (f32x4){0.f, 0.f, 0.f, 0.f};

    const int qloc = w * 16 + l15;
    const int swA0 = (lg ^ (qloc & 7)) << 3;
    const int swA1 = ((lg + 4) ^ (qloc & 7)) << 3;

    stageKV(0, 0);
    float skn[4];
#pragma unroll
    for (int c = 0; c < 4; ++c) skn[c] = sk[bhS + c * 16 + l15];
    asm volatile("s_waitcnt vmcnt(0)" ::: "memory");
    __builtin_amdgcn_s_barrier();

    int nb = 0;
    for (int kt = 0; kt < nkt; ++kt) {
      const int k0 = kt * KB;
      float skc[4];
#pragma unroll
      for (int c = 0; c < 4; ++c) skc[c] = skn[c];
      if (kt + 1 < nkt) {
        stageKV(kt + 1, nb ^ 1);
#pragma unroll
        for (int c = 0; c < 4; ++c)
          skn[c] = sk[bhS + (kt + 1) * KB + c * 16 + l15];
      }
      const bool diag = (kt == nkt - 1);

      float s2v[4][4];
      float tmax[4] = {-3.0e38f, -3.0e38f, -3.0e38f, -3.0e38f};
      __builtin_amdgcn_s_setprio(1);
#pragma unroll
      for (int c = 0; c < 4; ++c) {
        const int krow = c * 16 + l15;
        const i32x4 b0 = *(const i32x4*)(ks[nb] + krow * 128 + ((lg ^ (krow & 7)) << 4));
        const i32x4 b1 = *(const i32x4*)(ks[nb] + krow * 128 + (((lg + 4) ^ (krow & 7)) << 4));
        i32x4 acc = {0, 0, 0, 0};
        acc = __builtin_amdgcn_mfma_i32_16x16x64_i8(qa0, b0, acc, 0, 0, 0);
        acc = __builtin_amdgcn_mfma_i32_16x16x64_i8(qa1, b1, acc, 0, 0, 0);
        const int kgl = k0 + krow;
#pragma unroll
        for (int r = 0; r < 4; ++r) {
          const bool valid = !diag || (kgl <= qg[r]);
          const float s2 = valid ? ((float)acc[r] * sqv[r] * skc[c]) : -3.0e38f;
          s2v[c][r] = s2;
          tmax[r] = fmaxf(tmax[r], s2);
        }
      }
      __builtin_amdgcn_s_setprio(0);
#pragma unroll
      for (int r = 0; r < 4; ++r)
#pragma unroll
        for (int off = 1; off < 16; off <<= 1)
          tmax[r] = fmaxf(tmax[r], __shfl_xor(tmax[r], off));

#pragma unroll
      for (int r = 0; r < 4; ++r) {
        if (tmax[r] > m_run[r] + 8.0f) {
          const float f = exp2f(m_run[r] - tmax[r]);
          m_run[r] = tmax[r];
          rs[r] *= f;
#pragma unroll
          for (int ds = 0; ds < 8; ++ds) oacc[ds][r] *= f;
        }
      }

#pragma unroll
      for (int c = 0; c < 4; ++c) {
        const int krow = c * 16 + l15;
#pragma unroll
        for (int r = 0; r < 4; ++r) {
          const float e = exp2f(s2v[c][r] - m_run[r]);
          rs[r] += e;
          const float p = rintf(e * 127.0f);
          const int qr = w * 16 + lg * 4 + r;
          const int sidx = (((krow >> 3) ^ (qr & 7)) << 3) | (krow & 7);
          ps[qr][sidx] = f2bf(p);
        }
      }

      const bf16x8 a0 = *(const bf16x8*)&ps[qloc][swA0];
      const bf16x8 a1 = *(const bf16x8*)&ps[qloc][swA1];
      __builtin_amdgcn_s_setprio(1);
#pragma unroll
      for (int ds = 0; ds < 8; ++ds) {
        const int d = ds * 16 + l15;
        const bf16x8 bv0 = *(const bf16x8*)(vs[nb] + d * 64 + ((lg ^ (d & 7)) << 3));
        const bf16x8 bv1 = *(const bf16x8*)(vs[nb] + d * 64 + (((lg + 4) ^ (d & 7)) << 3));
        oacc[ds] = __builtin_amdgcn_mfma_f32_16x16x32_bf16(a0, bv0, oacc[ds], 0, 0, 0);
        oacc[ds] = __builtin_amdgcn_mfma_f32_16x16x32_bf16(a1, bv1, oacc[ds], 0, 0, 0);
      }
      __builtin_amdgcn_s_setprio(0);
      asm volatile("s_waitcnt vmcnt(0)" ::: "memory");
      __builtin_amdgcn_s_barrier();
      nb ^= 1;
    }

#pragma unroll
    for (int r = 0; r < 4; ++r)
#pragma unroll
      for (int off = 1; off < 16; off <<= 1)
        rs[r] += __shfl_xor(rs[r], off);

#pragma unroll
    for (int r = 0; r < 4; ++r) {
      const float inv = 1.0f / (127.0f * rs[r]);
      float* op = attn + ((size_t)(b * S_LEN + qg[r])) * HDIM + h * DHEAD + l15;
#pragma unroll
      for (int ds = 0; ds < 8; ++ds)
        op[ds * 16] = oacc[ds][r] * inv;
    }
  }
}

extern "C" void kernel_launch(void* const* d_in, const int* in_sizes, int n_in,
                              void* d_out, int out_size, void* d_ws, size_t ws_size,
                              hipStream_t stream) {
  const float* hs = (const float*)d_in[0];
  const float* wmat[4] = { (const float*)d_in[1], (const float*)d_in[2],
                           (const float*)d_in[3], (const float*)d_in[4] };

  char* p = (char*)d_ws;
  auto take = [&](size_t sz) { char* r = p; p += (sz + 255) & ~(size_t)255; return r; };

  int8_t* xq8 = (int8_t*)take((size_t)MTOK * HDIM);
  int8_t* w4[4];
  for (int i = 0; i < 4; ++i) w4[i] = (int8_t*)take((size_t)HDIM * HDIM);
  float* sx = (float*)take((size_t)MTOK * 4);
  float* sw[4];
  for (int i = 0; i < 4; ++i) sw[i] = (float*)take((size_t)HDIM * 4);
  float* y = (float*)take((size_t)MTOK * HDIM * 4);
  int8_t* qq8 = (int8_t*)take((size_t)MTOK * HDIM);
  int8_t* kq8 = (int8_t*)take((size_t)MTOK * HDIM);
  unsigned short* vqT = (unsigned short*)take((size_t)MTOK * HDIM * 2);
  float* sqs = (float*)take((size_t)BATCH * NHEAD * S_LEN * 4);
  float* sks = (float*)take((size_t)BATCH * NHEAD * S_LEN * 4);
  float* sattn = (float*)take((size_t)MTOK * 4);
  float* ctab = (float*)take((size_t)S_LEN * 64 * 4);
  float* stab = (float*)take((size_t)S_LEN * 64 * 4);

  prequant_kernel<<<MTOK + 4 * HDIM + 256, 256, 0, stream>>>(
      hs, wmat[0], wmat[1], wmat[2], wmat[3],
      xq8, w4[0], w4[1], w4[2], w4[3],
      sx, sw[0], sw[1], sw[2], sw[3], ctab, stab);

  const dim3 gg(HDIM / 128, MTOK / 128);  // 512 blocks
  gemm_i8_fused_kernel<1><<<gg, 256, 0, stream>>>(
      xq8, sx, w4[0], sw[0], nullptr, qq8, sqs, ctab, stab, nullptr);
  gemm_i8_fused_kernel<1><<<gg, 256, 0, stream>>>(
      xq8, sx, w4[1], sw[1], nullptr, kq8, sks, ctab, stab, nullptr);
  gemm_i8_fused_kernel<2><<<gg, 256, 0, stream>>>(
      xq8, sx, w4[2], sw[2], nullptr, nullptr, nullptr, nullptr, nullptr, vqT);

  attn_mfma_kernel<<<512, 256, 0, stream>>>(qq8, sqs, kq8, sks, vqT, y);

  rowquant_kernel<<<MTOK, 256, 0, stream>>>(y, xq8, sattn, 127.f, -128.f);
  gemm_i8_fused_kernel<0><<<gg, 256, 0, stream>>>(
      xq8, sattn, w4[3], sw[3], (float*)d_out, nullptr, nullptr, nullptr, nullptr, nullptr);
}

// Round 18
// 283.720 us; speedup vs baseline: 1.0979x; 1.0084x over previous
//
#include <hip/hip_runtime.h>
#include <stdint.h>

#define S_LEN 1024
#define HDIM  4096
#define NHEAD 32
#define DHEAD 128
#define BATCH 2
#define MTOK  (BATCH * S_LEN)   // 2048

typedef __attribute__((ext_vector_type(4))) int   i32x4;
typedef __attribute__((ext_vector_type(4))) float f32x4;
typedef __attribute__((ext_vector_type(8))) short bf16x8;

#define GLOBAL_AS __attribute__((address_space(1)))
#define LDS_AS    __attribute__((address_space(3)))

__device__ __forceinline__ void gl2lds16(const void* g, void* l) {
  __builtin_amdgcn_global_load_lds((const GLOBAL_AS unsigned int*)(g),
                                   (LDS_AS unsigned int*)(l), 16, 0, 0);
}

// float -> bf16 bits, round-to-nearest-even
__device__ __forceinline__ unsigned short f2bf(float f) {
  unsigned int u = __float_as_uint(f);
  unsigned int r = (u + 0x7fffu + ((u >> 16) & 1u)) >> 16;
  return (unsigned short)r;
}
__device__ __forceinline__ float bf2f_lo(int w) {
  return __uint_as_float(((unsigned)w & 0xffffu) << 16);
}
__device__ __forceinline__ float bf2f_hi(int w) {
  return __uint_as_float((unsigned)w & 0xffff0000u);
}

#define PIN4(v) asm volatile("" : "+v"(v.x), "+v"(v.y), "+v"(v.z), "+v"(v.w))

// non-temporal float4 load (read-once streams: keep out of caches)
__device__ __forceinline__ float4 ld_nt4(const float4* p) {
  const f32x4 t = __builtin_nontemporal_load((const f32x4*)p);
  float4 r; r.x = t[0]; r.y = t[1]; r.z = t[2]; r.w = t[3];
  return r;
}

// -------- merged input fake-quant + rope-table build (extra 256 blocks) --------
__global__ __launch_bounds__(256) void prequant_kernel(
    const float* __restrict__ hs,
    const float* __restrict__ w0, const float* __restrict__ w1,
    const float* __restrict__ w2, const float* __restrict__ w3,
    int8_t* __restrict__ xq8,
    int8_t* __restrict__ q0, int8_t* __restrict__ q1,
    int8_t* __restrict__ q2, int8_t* __restrict__ q3,
    float* __restrict__ sx,
    float* __restrict__ s0, float* __restrict__ s1,
    float* __restrict__ s2, float* __restrict__ s3,
    float* __restrict__ ctab, float* __restrict__ stab)
{
  const int row = blockIdx.x;
  if (row >= MTOK + 4 * HDIM) {
    const int t = (row - (MTOK + 4 * HDIM)) * 256 + threadIdx.x;
    const int s = t >> 6, d = t & 63;
    const float inv = powf(10000.0f, -(float)d * (1.0f / 64.0f));
    const float ang = (float)s * inv;
    float sn, c;
    sincosf(ang, &sn, &c);
    ctab[t] = c;
    stab[t] = sn;
    return;
  }
  const float* src; int8_t* dst; float* sc; float qmax, clipLo; int lrow;
  if (row < MTOK) {
    src = hs; dst = xq8; sc = sx; qmax = 127.f; clipLo = -128.f; lrow = row;
  } else {
    const int wi = (row - MTOK) >> 12;
    lrow = (row - MTOK) & 4095;
    qmax = 7.f; clipLo = -8.f;
    src = (wi == 0) ? w0 : (wi == 1) ? w1 : (wi == 2) ? w2 : w3;
    dst = (wi == 0) ? q0 : (wi == 1) ? q1 : (wi == 2) ? q2 : q3;
    sc  = (wi == 0) ? s0 : (wi == 1) ? s1 : (wi == 2) ? s2 : s3;
  }
  const int t = threadIdx.x;
  const float4* xr = (const float4*)(src + (size_t)lrow * HDIM);
  float4 v[4];
  float am = 0.f;
#pragma unroll
  for (int i = 0; i < 4; ++i) {
    v[i] = ld_nt4(xr + t + 256 * i);
    am = fmaxf(am, fmaxf(fmaxf(fabsf(v[i].x), fabsf(v[i].y)),
                         fmaxf(fabsf(v[i].z), fabsf(v[i].w))));
  }
#pragma unroll
  for (int i = 0; i < 4; ++i) PIN4(v[i]);
#pragma unroll
  for (int off = 32; off > 0; off >>= 1) am = fmaxf(am, __shfl_down(am, off));
  __shared__ float wred[4];
  if ((t & 63) == 0) wred[t >> 6] = am;
  __syncthreads();
  const float m = fmaxf(fmaxf(wred[0], wred[1]), fmaxf(wred[2], wred[3]));
  const float scale = fmaxf(m / qmax, 1e-8f);
  const float inv = 1.0f / scale;
  if (t == 0) sc[lrow] = scale;
  int* qo = (int*)(dst + (size_t)lrow * HDIM);
#pragma unroll
  for (int i = 0; i < 4; ++i) {
    const int b0 = (int)fminf(fmaxf(rintf(v[i].x * inv), clipLo), qmax);
    const int b1 = (int)fminf(fmaxf(rintf(v[i].y * inv), clipLo), qmax);
    const int b2 = (int)fminf(fmaxf(rintf(v[i].z * inv), clipLo), qmax);
    const int b3 = (int)fminf(fmaxf(rintf(v[i].w * inv), clipLo), qmax);
    qo[t + 256 * i] = (b0 & 0xff) | ((b1 & 0xff) << 8) | ((b2 & 0xff) << 16) | ((b3 & 0xff) << 24);
  }
}

// -------- per-row fake-quant for attn output (bf16 input) --------
__global__ __launch_bounds__(256) void rowquant_bf_kernel(
    const unsigned short* __restrict__ y, int8_t* __restrict__ q,
    float* __restrict__ scales)
{
  const int row = blockIdx.x;
  const int t = threadIdx.x;
  const i32x4* xr = (const i32x4*)(y + (size_t)row * HDIM);   // 8 bf16 / 16B
  i32x4 u[2];
  u[0] = xr[t];
  u[1] = xr[t + 256];
  float am = 0.f;
#pragma unroll
  for (int j = 0; j < 2; ++j)
#pragma unroll
    for (int k = 0; k < 4; ++k) {
      am = fmaxf(am, fmaxf(fabsf(bf2f_lo(u[j][k])), fabsf(bf2f_hi(u[j][k]))));
    }
#pragma unroll
  for (int off = 32; off > 0; off >>= 1) am = fmaxf(am, __shfl_down(am, off));
  __shared__ float wred[4];
  if ((t & 63) == 0) wred[t >> 6] = am;
  __syncthreads();
  const float m = fmaxf(fmaxf(wred[0], wred[1]), fmaxf(wred[2], wred[3]));
  const float scale = fmaxf(m * (1.0f / 127.0f), 1e-8f);
  const float inv = 1.0f / scale;
  if (t == 0) scales[row] = scale;
  // chunk c = t + 256*j covers elements c*8 .. c*8+7 -> 8 int8 = 2 dwords
  int* qo = (int*)(q + (size_t)row * HDIM);
#pragma unroll
  for (int j = 0; j < 2; ++j) {
    const int c = t + 256 * j;
    int dw[2];
#pragma unroll
    for (int half = 0; half < 2; ++half) {
      int pk = 0;
#pragma unroll
      for (int k = 0; k < 2; ++k) {
        const int w32 = u[j][half * 2 + k];
        const int b0 = (int)fminf(fmaxf(rintf(bf2f_lo(w32) * inv), -128.f), 127.f);
        const int b1 = (int)fminf(fmaxf(rintf(bf2f_hi(w32) * inv), -128.f), 127.f);
        pk |= (b0 & 0xff) << (16 * k);
        pk |= (b1 & 0xff) << (16 * k + 8);
      }
      dw[half] = pk;
    }
    *(int2*)(qo + c * 2) = make_int2(dw[0], dw[1]);
  }
}

// ======== i8 MFMA GEMM, 128x128 tile, 4 waves, 2-phase dbuf, fused epilogue ========
// MODE 0: C write (f32).  MODE 1: rope + per-(token,head) quant8 -> o8/oscale.
// MODE 2: per-(token,head) quant + fold scale + transposed bf16 -> vqT.
template<int MODE>
__global__ __launch_bounds__(256, 2) void gemm_i8_fused_kernel(
    const int8_t* __restrict__ A, const float* __restrict__ sa,
    const int8_t* __restrict__ Bw, const float* __restrict__ sb,
    float* __restrict__ C,
    int8_t* __restrict__ o8, float* __restrict__ oscale,
    const float* __restrict__ ctab, const float* __restrict__ stab,
    unsigned short* __restrict__ vqT)
{
  __shared__ __align__(16) char smem[128 * 129 * 4];   // 66048 B (dbuf 64KB aliased)
  __shared__ float vscale[128];
  __shared__ float vinv[128];
  int8_t (*asB)[128 * 128] = (int8_t(*)[128 * 128])smem;
  int8_t (*bsB)[128 * 128] = (int8_t(*)[128 * 128])(smem + 32768);
  float (*fx)[129] = (float(*)[129])smem;

  const int flat = blockIdx.y * gridDim.x + blockIdx.x;
  const int nf = (flat & 7) * 64 + (flat >> 3);
  const int bmi = nf & 15, bni = nf >> 4;
  const int bm = bmi * 128, bn = bni * 128;

  const int tid = threadIdx.x;
  const int w = tid >> 6, l = tid & 63;
  const int l15 = l & 15, lg = l >> 4, l7 = l & 7;
  const int lr = l >> 3, g7 = l & 7;
  const int m0 = (w >> 1) * 64, n0 = (w & 1) * 64;

  const int8_t* aT = A + (size_t)(bm + lr) * HDIM + ((g7 ^ lr) << 4);
  const int8_t* bT = Bw + (size_t)(bn + lr) * HDIM + ((g7 ^ lr) << 4);

  i32x4 acc[4][4];
#pragma unroll
  for (int i = 0; i < 4; ++i)
#pragma unroll
    for (int j = 0; j < 4; ++j) acc[i][j] = (i32x4){0, 0, 0, 0};

  auto stage = [&](int t) {
    const int bf = t & 1;
    const size_t k = (size_t)t * 128;
#pragma unroll
    for (int i = 0; i < 4; ++i) {
      const int r0 = w * 32 + i * 8;
      gl2lds16(aT + (size_t)r0 * HDIM + k, asB[bf] + r0 * 128);
      gl2lds16(bT + (size_t)r0 * HDIM + k, bsB[bf] + r0 * 128);
    }
  };

  stage(0);
  asm volatile("s_waitcnt vmcnt(0)" ::: "memory");
  __builtin_amdgcn_s_barrier();

  for (int t = 0; t < 32; ++t) {
    if (t < 31) stage(t + 1);
    const int cur = t & 1;
    __builtin_amdgcn_s_setprio(1);
#pragma unroll
    for (int kk = 0; kk < 2; ++kk) {
      i32x4 aF[4], bF[4];
      const int slot = (((kk << 2) + lg) ^ l7) << 4;
#pragma unroll
      for (int i = 0; i < 4; ++i)
        aF[i] = *(const i32x4*)(asB[cur] + (m0 + i * 16 + l15) * 128 + slot);
#pragma unroll
      for (int j = 0; j < 4; ++j)
        bF[j] = *(const i32x4*)(bsB[cur] + (n0 + j * 16 + l15) * 128 + slot);
#pragma unroll
      for (int i = 0; i < 4; ++i)
#pragma unroll
        for (int j = 0; j < 4; ++j)
          acc[i][j] = __builtin_amdgcn_mfma_i32_16x16x64_i8(aF[i], bF[j], acc[i][j], 0, 0, 0);
    }
    __builtin_amdgcn_s_setprio(0);
    if (t < 31) {
      asm volatile("s_waitcnt vmcnt(0)" ::: "memory");
      __builtin_amdgcn_s_barrier();
    }
  }

  float sbr[4];
#pragma unroll
  for (int j = 0; j < 4; ++j) sbr[j] = sb[bn + n0 + j * 16 + l15];

  if (MODE == 0) {
#pragma unroll
    for (int i = 0; i < 4; ++i) {
#pragma unroll
      for (int r = 0; r < 4; ++r) {
        const int m = bm + m0 + i * 16 + lg * 4 + r;
        const float sm = sa[m];
        float* cp = C + (size_t)m * HDIM + bn + n0 + l15;
#pragma unroll
        for (int j = 0; j < 4; ++j)
          cp[j * 16] = sm * sbr[j] * (float)acc[i][j][r];
      }
    }
    return;
  }

  // ---- scatter scaled f32 tile to LDS ----
  __syncthreads();
#pragma unroll
  for (int i = 0; i < 4; ++i) {
#pragma unroll
    for (int r = 0; r < 4; ++r) {
      const int ml = m0 + i * 16 + lg * 4 + r;
      const float sm = sa[bm + ml];
#pragma unroll
      for (int j = 0; j < 4; ++j)
        fx[ml][n0 + j * 16 + l15] = sm * sbr[j] * (float)acc[i][j][r];
    }
  }
  __syncthreads();

  const int h = bn >> 7;   // one head per block (BN == DHEAD)

  if (MODE == 1) {
    const int row = tid >> 1, half = tid & 1;
    const int sg = bm + row;
    const int b = sg >> 10, s = sg & (S_LEN - 1);
    const float* ct = ctab + (size_t)s * 64;
    const float* st = stab + (size_t)s * 64;
    float am = 0.f;
#pragma unroll
    for (int d0 = 0; d0 < 64; ++d0) {
      const int d = half * 64 + d0;
      const float x0 = fx[row][d];
      const float x1 = fx[row][d ^ 64];
      const float c = ct[d0], sn = st[d0];
      const float v = half ? (x0 * c + x1 * sn) : (x0 * c - x1 * sn);
      fx[row][d] = v;
      am = fmaxf(am, fabsf(v));
    }
    am = fmaxf(am, __shfl_xor(am, 1));
    const float scale = fmaxf(am * (1.0f / 127.0f), 1e-8f);
    const float inv = 1.0f / scale;
    int8_t* op = o8 + (((size_t)(b * NHEAD + h)) * S_LEN + s) * DHEAD + half * 64;
#pragma unroll
    for (int c4 = 0; c4 < 4; ++c4) {
      i32x4 dw;
#pragma unroll
      for (int u = 0; u < 4; ++u) {
        int pk = 0;
#pragma unroll
        for (int bi = 0; bi < 4; ++bi) {
          const float v = fx[row][half * 64 + c4 * 16 + u * 4 + bi];
          const int q = (int)fminf(fmaxf(rintf(v * inv), -128.f), 127.f);
          pk |= (q & 0xff) << (8 * bi);
        }
        dw[u] = pk;
      }
      *(i32x4*)(op + c4 * 16) = dw;
    }
    if (!half) oscale[((size_t)(b * NHEAD + h)) * S_LEN + s] = scale;
  } else {
    {
      const int row = tid >> 1, half = tid & 1;
      float am = 0.f;
#pragma unroll
      for (int d0 = 0; d0 < 64; ++d0)
        am = fmaxf(am, fabsf(fx[row][half * 64 + d0]));
      am = fmaxf(am, __shfl_xor(am, 1));
      if (!half) {
        const float s = fmaxf(am * (1.0f / 127.0f), 1e-8f);
        vscale[row] = s;
        vinv[row] = 1.0f / s;
      }
    }
    __syncthreads();
    {
      const int d = tid >> 1, sh = tid & 1;
      const int b = bm >> 10;
      const int bh = b * NHEAD + h;
      unsigned short* op = vqT + ((size_t)bh * DHEAD + d) * S_LEN + (bm & (S_LEN - 1)) + sh * 64;
#pragma unroll
      for (int c8 = 0; c8 < 8; ++c8) {
        i32x4 dw;
#pragma unroll
        for (int u = 0; u < 4; ++u) {
          const int sl = sh * 64 + c8 * 8 + u * 2;
          const float sc0 = vscale[sl], sc1 = vscale[sl + 1];
          const float q0 = fminf(fmaxf(rintf(fx[sl][d] * vinv[sl]), -128.f), 127.f);
          const float q1 = fminf(fmaxf(rintf(fx[sl + 1][d] * vinv[sl + 1]), -128.f), 127.f);
          dw[u] = (int)f2bf(q0 * sc0) | ((int)f2bf(q1 * sc1) << 16);
        }
        *(i32x4*)(op + c8 * 8) = dw;
      }
    }
  }
}

// -------- single-pass online attn, K/V double-buffered, defer-max; bf16 y out --------
#define QB 64
#define KB 64

__global__ __launch_bounds__(256) void attn_mfma_kernel(
    const int8_t* __restrict__ qq, const float* __restrict__ sq,
    const int8_t* __restrict__ kq, const float* __restrict__ sk,
    const unsigned short* __restrict__ vqT,   // bf16 bits, sv pre-folded
    unsigned short* __restrict__ attn)        // bf16 out
{
  __shared__ __align__(16) int8_t ks[2][KB * 128];
  __shared__ __align__(16) unsigned short vs[2][128 * 64];
  __shared__ __align__(16) unsigned short ps[QB][64];

  const int tid = threadIdx.x;
  const int w = tid >> 6;
  const int l = tid & 63;
  const int l15 = l & 15;
  const int lg = l >> 4;
  const int lr = l >> 3, g7 = l & 7;
  const int bflat = blockIdx.x;
  const int bh = (bflat & 7) + 8 * (bflat >> 6);
  const int qxb = (bflat >> 3) & 7;
  const size_t bhS = (size_t)bh * S_LEN;
  const int b = bh >> 5, h = bh & 31;
  const int NT = S_LEN / QB;

  auto stageKV = [&](int kt, int nb) {
    const int k0 = kt * KB;
#pragma unroll
    for (int i = 0; i < 2; ++i) {
      const int r0 = w * 16 + i * 8;
      gl2lds16(kq + (bhS + k0 + r0 + lr) * (size_t)128 + ((g7 ^ lr) << 4),
               ks[nb] + r0 * 128);
    }
#pragma unroll
    for (int i = 0; i < 4; ++i) {
      const int r0 = w * 32 + i * 8;
      gl2lds16(vqT + ((size_t)bh * 128 + r0 + lr) * S_LEN + k0 + ((g7 ^ lr) << 3),
               vs[nb] + r0 * 64);
    }
  };

  for (int rep = 0; rep < 2; ++rep) {
    const int qt = rep ? (NT - 1 - qxb) : qxb;
    const int q0 = qt * QB;
    const int nkt = qt + 1;

    const int qrow = q0 + w * 16 + l15;
    const int8_t* qp = qq + (bhS + qrow) * (size_t)DHEAD;
    const i32x4 qa0 = *(const i32x4*)(qp + lg * 16);
    const i32x4 qa1 = *(const i32x4*)(qp + 64 + lg * 16);

    float sqv[4];
    int qg[4];
#pragma unroll
    for (int r = 0; r < 4; ++r) {
      qg[r] = q0 + w * 16 + lg * 4 + r;
      sqv[r] = sq[bhS + qg[r]] * 0.08838834764831843f * 1.4426950408889634f;
    }

    float m_run[4] = {-3.0e38f, -3.0e38f, -3.0e38f, -3.0e38f};
    float rs[4] = {0.f, 0.f, 0.f, 0.f};
    f32x4 oacc[8];
#pragma unroll
    for (int ds = 0; ds < 8; ++ds) oacc[ds] = (f32x4){0.f, 0.f, 0.f, 0.f};

    const int qloc = w * 16 + l15;
    const int swA0 = (lg ^ (qloc & 7)) << 3;
    const int swA1 = ((lg + 4) ^ (qloc & 7)) << 3;

    stageKV(0, 0);
    float skn[4];
#pragma unroll
    for (int c = 0; c < 4; ++c) skn[c] = sk[bhS + c * 16 + l15];
    asm volatile("s_waitcnt vmcnt(0)" ::: "memory");
    __builtin_amdgcn_s_barrier();

    int nb = 0;
    for (int kt = 0; kt < nkt; ++kt) {
      const int k0 = kt * KB;
      float skc[4];
#pragma unroll
      for (int c = 0; c < 4; ++c) skc[c] = skn[c];
      if (kt + 1 < nkt) {
        stageKV(kt + 1, nb ^ 1);
#pragma unroll
        for (int c = 0; c < 4; ++c)
          skn[c] = sk[bhS + (kt + 1) * KB + c * 16 + l15];
      }
      const bool diag = (kt == nkt - 1);

      float s2v[4][4];
      float tmax[4] = {-3.0e38f, -3.0e38f, -3.0e38f, -3.0e38f};
      __builtin_amdgcn_s_setprio(1);
#pragma unroll
      for (int c = 0; c < 4; ++c) {
        const int krow = c * 16 + l15;
        const i32x4 b0 = *(const i32x4*)(ks[nb] + krow * 128 + ((lg ^ (krow & 7)) << 4));
        const i32x4 b1 = *(const i32x4*)(ks[nb] + krow * 128 + (((lg + 4) ^ (krow & 7)) << 4));
        i32x4 acc = {0, 0, 0, 0};
        acc = __builtin_amdgcn_mfma_i32_16x16x64_i8(qa0, b0, acc, 0, 0, 0);
        acc = __builtin_amdgcn_mfma_i32_16x16x64_i8(qa1, b1, acc, 0, 0, 0);
        const int kgl = k0 + krow;
#pragma unroll
        for (int r = 0; r < 4; ++r) {
          const bool valid = !diag || (kgl <= qg[r]);
          const float s2 = valid ? ((float)acc[r] * sqv[r] * skc[c]) : -3.0e38f;
          s2v[c][r] = s2;
          tmax[r] = fmaxf(tmax[r], s2);
        }
      }
      __builtin_amdgcn_s_setprio(0);
#pragma unroll
      for (int r = 0; r < 4; ++r)
#pragma unroll
        for (int off = 1; off < 16; off <<= 1)
          tmax[r] = fmaxf(tmax[r], __shfl_xor(tmax[r], off));

#pragma unroll
      for (int r = 0; r < 4; ++r) {
        if (tmax[r] > m_run[r] + 8.0f) {
          const float f = exp2f(m_run[r] - tmax[r]);
          m_run[r] = tmax[r];
          rs[r] *= f;
#pragma unroll
          for (int ds = 0; ds < 8; ++ds) oacc[ds][r] *= f;
        }
      }

#pragma unroll
      for (int c = 0; c < 4; ++c) {
        const int krow = c * 16 + l15;
#pragma unroll
        for (int r = 0; r < 4; ++r) {
          const float e = exp2f(s2v[c][r] - m_run[r]);
          rs[r] += e;
          const float p = rintf(e * 127.0f);
          const int qr = w * 16 + lg * 4 + r;
          const int sidx = (((krow >> 3) ^ (qr & 7)) << 3) | (krow & 7);
          ps[qr][sidx] = f2bf(p);
        }
      }

      const bf16x8 a0 = *(const bf16x8*)&ps[qloc][swA0];
      const bf16x8 a1 = *(const bf16x8*)&ps[qloc][swA1];
      __builtin_amdgcn_s_setprio(1);
#pragma unroll
      for (int ds = 0; ds < 8; ++ds) {
        const int d = ds * 16 + l15;
        const bf16x8 bv0 = *(const bf16x8*)(vs[nb] + d * 64 + ((lg ^ (d & 7)) << 3));
        const bf16x8 bv1 = *(const bf16x8*)(vs[nb] + d * 64 + (((lg + 4) ^ (d & 7)) << 3));
        oacc[ds] = __builtin_amdgcn_mfma_f32_16x16x32_bf16(a0, bv0, oacc[ds], 0, 0, 0);
        oacc[ds] = __builtin_amdgcn_mfma_f32_16x16x32_bf16(a1, bv1, oacc[ds], 0, 0, 0);
      }
      __builtin_amdgcn_s_setprio(0);
      asm volatile("s_waitcnt vmcnt(0)" ::: "memory");
      __builtin_amdgcn_s_barrier();
      nb ^= 1;
    }

#pragma unroll
    for (int r = 0; r < 4; ++r)
#pragma unroll
      for (int off = 1; off < 16; off <<= 1)
        rs[r] += __shfl_xor(rs[r], off);

#pragma unroll
    for (int r = 0; r < 4; ++r) {
      const float inv = 1.0f / (127.0f * rs[r]);
      unsigned short* op = attn + ((size_t)(b * S_LEN + qg[r])) * HDIM + h * DHEAD + l15;
#pragma unroll
      for (int ds = 0; ds < 8; ++ds)
        op[ds * 16] = f2bf(oacc[ds][r] * inv);
    }
  }
}

extern "C" void kernel_launch(void* const* d_in, const int* in_sizes, int n_in,
                              void* d_out, int out_size, void* d_ws, size_t ws_size,
                              hipStream_t stream) {
  const float* hs = (const float*)d_in[0];
  const float* wmat[4] = { (const float*)d_in[1], (const float*)d_in[2],
                           (const float*)d_in[3], (const float*)d_in[4] };

  char* p = (char*)d_ws;
  auto take = [&](size_t sz) { char* r = p; p += (sz + 255) & ~(size_t)255; return r; };

  int8_t* xq8 = (int8_t*)take((size_t)MTOK * HDIM);
  int8_t* w4[4];
  for (int i = 0; i < 4; ++i) w4[i] = (int8_t*)take((size_t)HDIM * HDIM);
  float* sx = (float*)take((size_t)MTOK * 4);
  float* sw[4];
  for (int i = 0; i < 4; ++i) sw[i] = (float*)take((size_t)HDIM * 4);
  unsigned short* y = (unsigned short*)take((size_t)MTOK * HDIM * 2);  // bf16
  int8_t* qq8 = (int8_t*)take((size_t)MTOK * HDIM);
  int8_t* kq8 = (int8_t*)take((size_t)MTOK * HDIM);
  unsigned short* vqT = (unsigned short*)take((size_t)MTOK * HDIM * 2);
  float* sqs = (float*)take((size_t)BATCH * NHEAD * S_LEN * 4);
  float* sks = (float*)take((size_t)BATCH * NHEAD * S_LEN * 4);
  float* sattn = (float*)take((size_t)MTOK * 4);
  float* ctab = (float*)take((size_t)S_LEN * 64 * 4);
  float* stab = (float*)take((size_t)S_LEN * 64 * 4);

  prequant_kernel<<<MTOK + 4 * HDIM + 256, 256, 0, stream>>>(
      hs, wmat[0], wmat[1], wmat[2], wmat[3],
      xq8, w4[0], w4[1], w4[2], w4[3],
      sx, sw[0], sw[1], sw[2], sw[3], ctab, stab);

  const dim3 gg(HDIM / 128, MTOK / 128);  // 512 blocks
  gemm_i8_fused_kernel<1><<<gg, 256, 0, stream>>>(
      xq8, sx, w4[0], sw[0], nullptr, qq8, sqs, ctab, stab, nullptr);
  gemm_i8_fused_kernel<1><<<gg, 256, 0, stream>>>(
      xq8, sx, w4[1], sw[1], nullptr, kq8, sks, ctab, stab, nullptr);
  gemm_i8_fused_kernel<2><<<gg, 256, 0, stream>>>(
      xq8, sx, w4[2], sw[2], nullptr, nullptr, nullptr, nullptr, nullptr, vqT);

  attn_mfma_kernel<<<512, 256, 0, stream>>>(qq8, sqs, kq8, sks, vqT, y);

  rowquant_bf_kernel<<<MTOK, 256, 0, stream>>>(y, xq8, sattn);
  gemm_i8_fused_kernel<0><<<gg, 256, 0, stream>>>(
      xq8, sattn, w4[3], sw[3], (float*)d_out, nullptr, nullptr, nullptr, nullptr, nullptr);
}